// Round 4
// baseline (190.340 us; speedup 1.0000x reference)
//
#include <hip/hip_runtime.h>
#include <hip/hip_bf16.h>

#define Bn 16
#define Cn 2048
#define Qn 128
#define En 200
#define Fn 800
#define On 128
#define EP 208  // padded e-rows for xcT

typedef float f32x4 __attribute__((ext_vector_type(4)));
typedef __bf16 bf16x8 __attribute__((ext_vector_type(8)));

__device__ __forceinline__ unsigned short f2bf(float f) {
    union { float f; unsigned u; } v; v.f = f;
    unsigned r = v.u + 0x7FFF + ((v.u >> 16) & 1);
    return (unsigned short)(r >> 16);
}
__device__ __forceinline__ float bf2f(unsigned short h) {
    union { unsigned u; float f; } v; v.u = (unsigned)h << 16;
    return v.f;
}

// ---- k_yq: yq_bf[b,q,e] = bf16(xq*w3 + w1); s_q[b,q] = dot(xq, w2) --------
__global__ void k_yq(const float* __restrict__ xq, const float* __restrict__ wsim,
                     unsigned short* __restrict__ yqb, float* __restrict__ s_q) {
    int wid = (blockIdx.x * blockDim.x + threadIdx.x) >> 6;
    int lane = threadIdx.x & 63;
    if (wid >= Bn * Qn) return;
    const float* xrow = xq + (size_t)wid * En;
    float s = 0.f;
    for (int e = lane; e < En; e += 64) {
        float x = xrow[e];
        yqb[(size_t)wid * En + e] = f2bf(x * wsim[400 + e] + wsim[e]);
        s += x * wsim[200 + e];
    }
    for (int i = 32; i; i >>= 1) s += __shfl_xor(s, i, 64);
    if (lane == 0) s_q[wid] = s;
}

// ---- k_cast_xc: xc fp32 -> bf16 (same layout) -----------------------------
__global__ void k_cast_xc(const float* __restrict__ xc, unsigned short* __restrict__ xcb) {
    int gid = blockIdx.x * 256 + threadIdx.x;
    int base = gid * 4;
    if (base >= Bn * Cn * En) return;
    float4 v = *(const float4*)(xc + base);
    ushort4 o;
    o.x = f2bf(v.x); o.y = f2bf(v.y); o.z = f2bf(v.z); o.w = f2bf(v.w);
    *(ushort4*)(xcb + base) = o;
}

// ---- k_prep_wp: w_proj -> bf16 [128][800] ---------------------------------
__global__ void k_prep_wp(const float* __restrict__ wp, unsigned short* __restrict__ wpb) {
    int gid = blockIdx.x * 256 + threadIdx.x;
    int base = gid * 4;
    if (base >= On * Fn) return;
    float4 v = *(const float4*)(wp + base);
    ushort4 o;
    o.x = f2bf(v.x); o.y = f2bf(v.y); o.z = f2bf(v.z); o.w = f2bf(v.w);
    *(ushort4*)(wpb + base) = o;
}

// ---- k_scores_mfma: scores = xc_bf @ yq_bf^T + s_q; fused row softmax -----
__global__ __launch_bounds__(256) void k_scores_mfma(const unsigned short* __restrict__ xcb,
                                                     const unsigned short* __restrict__ yqb,
                                                     const float* __restrict__ s_q,
                                                     float* __restrict__ scores,
                                                     unsigned short* __restrict__ s1) {
    int b = blockIdx.y, c0 = blockIdx.x * 64;
    int w = threadIdx.x >> 6, lane = threadIdx.x & 63;
    int lrow = lane & 15, kg = lane >> 4;
    const unsigned short* Ab = xcb + ((size_t)(b * Cn + c0 + w * 16 + lrow)) * En + kg * 8;
    const unsigned short* Bb = yqb + ((size_t)(b * Qn + lrow)) * En + kg * 8;
    f32x4 acc[8] = {};
#pragma unroll
    for (int kc = 0; kc < 7; ++kc) {   // K=200: 6 full chunks + tail (kg==0 only)
        bool valid = (kc < 6) || (kg == 0);
        bf16x8 af = bf16x8{0,0,0,0,0,0,0,0};
        if (valid) af = *(const bf16x8*)(Ab + kc * 32);
#pragma unroll
        for (int j = 0; j < 8; ++j) {
            bf16x8 bfr = bf16x8{0,0,0,0,0,0,0,0};
            if (valid) bfr = *(const bf16x8*)(Bb + (size_t)j * 16 * En + kc * 32);
            acc[j] = __builtin_amdgcn_mfma_f32_16x16x32_bf16(af, bfr, acc[j], 0, 0, 0);
        }
    }
#pragma unroll
    for (int j = 0; j < 8; ++j) {
        float sq = s_q[b * Qn + j * 16 + lrow];
#pragma unroll
        for (int r = 0; r < 4; ++r) acc[j][r] += sq;
    }
    size_t rowbase = (size_t)(b * Cn + c0 + w * 16 + kg * 4);
#pragma unroll
    for (int r = 0; r < 4; ++r)
#pragma unroll
        for (int j = 0; j < 8; ++j)
            scores[(rowbase + r) * Qn + j * 16 + lrow] = acc[j][r];
#pragma unroll
    for (int r = 0; r < 4; ++r) {
        float m = acc[0][r];
#pragma unroll
        for (int j = 1; j < 8; ++j) m = fmaxf(m, acc[j][r]);
        for (int d = 1; d < 16; d <<= 1) m = fmaxf(m, __shfl_xor(m, d, 64));
        float ssum = 0.f;
#pragma unroll
        for (int j = 0; j < 8; ++j) {
            float e_ = __expf(acc[j][r] - m);
            acc[j][r] = e_;
            ssum += e_;
        }
        for (int d = 1; d < 16; d <<= 1) ssum += __shfl_xor(ssum, d, 64);
        float si = 1.f / ssum;
#pragma unroll
        for (int j = 0; j < 8; ++j)
            s1[(rowbase + r) * Qn + j * 16 + lrow] = f2bf(acc[j][r] * si);
    }
}

// ---- k_colpart / k_colcomb ------------------------------------------------
__global__ void k_colpart(const float* __restrict__ scores,
                          float* __restrict__ cpM, float* __restrict__ cpS) {
    int b = blockIdx.y, cch = blockIdx.x;
    int q = threadIdx.x;
    const float* base = scores + (size_t)(b * Cn + cch * 128) * Qn + q;
    float m = -1e30f, s = 0.f;
    for (int c = 0; c < 128; c++) {
        float x = base[(size_t)c * Qn];
        float nm = fmaxf(m, x);
        s = s * __expf(m - nm) + __expf(x - nm);
        m = nm;
    }
    cpM[(b * 16 + cch) * 128 + q] = m;
    cpS[(b * 16 + cch) * 128 + q] = s;
}

__global__ void k_colcomb(const float* __restrict__ cpM, const float* __restrict__ cpS,
                          float* __restrict__ colM, float* __restrict__ colSi) {
    int b = blockIdx.x, q = threadIdx.x;
    float m = -1e30f;
    for (int k = 0; k < 16; k++) m = fmaxf(m, cpM[(b * 16 + k) * 128 + q]);
    float s = 0.f;
    for (int k = 0; k < 16; k++) s += cpS[(b * 16 + k) * 128 + q] * __expf(cpM[(b * 16 + k) * 128 + q] - m);
    colM[b * 128 + q] = m;
    colSi[b * 128 + q] = 1.f / s;
}

// ---- k_s2t: s2T[b][q][c] = bf16(exp(scores[c][q]-colM[q])*colSi[q]) -------
__global__ __launch_bounds__(256) void k_s2t(const float* __restrict__ scores,
                                             const float* __restrict__ colM,
                                             const float* __restrict__ colSi,
                                             unsigned short* __restrict__ s2T) {
    int ct = blockIdx.x, qt = blockIdx.y, b = blockIdx.z;
    int c0 = ct * 64, q0 = qt * 64;
    int tid = threadIdx.x;
    __shared__ float t[64][65];
    for (int i = tid; i < 64 * 64; i += 256) {
        int ci = i >> 6, qi = i & 63;
        t[ci][qi] = scores[((size_t)(b * Cn + c0 + ci)) * Qn + q0 + qi];
    }
    __syncthreads();
    for (int i = tid; i < 64 * 64; i += 256) {
        int qi = i >> 6, ci = i & 63;
        int q = q0 + qi;
        float v = __expf(t[ci][qi] - colM[b * Qn + q]) * colSi[b * Qn + q];
        s2T[((size_t)(b * Qn + q)) * Cn + c0 + ci] = f2bf(v);
    }
}

// ---- k_xcT: xcT[b][e][c] bf16 (rows 200..207 zero) ------------------------
__global__ __launch_bounds__(256) void k_xcT(const float* __restrict__ xc,
                                             unsigned short* __restrict__ xcT) {
    int ct = blockIdx.x, et = blockIdx.y, b = blockIdx.z;
    int c0 = ct * 64, e0 = et * 64;
    int tid = threadIdx.x;
    __shared__ float t[64][65];
    for (int i = tid; i < 64 * 64; i += 256) {
        int ci = i >> 6, ei = i & 63;
        int e = e0 + ei;
        t[ci][ei] = (e < En) ? xc[((size_t)(b * Cn + c0 + ci)) * En + e] : 0.f;
    }
    __syncthreads();
    for (int i = tid; i < 64 * 64; i += 256) {
        int ei = i >> 6, ci = i & 63;
        int e = e0 + ei;
        if (e < EP)
            xcT[((size_t)(b * EP + e)) * Cn + c0 + ci] = f2bf(t[ci][ei]);
    }
}

// ---- k_xqT: xqaT rows [0,200) = xq^T bf16 ---------------------------------
__global__ __launch_bounds__(256) void k_xqT(const float* __restrict__ xq,
                                             unsigned short* __restrict__ xqaT) {
    int et = blockIdx.x, qt = blockIdx.y, b = blockIdx.z;
    int e0 = et * 64, q0 = qt * 64;
    int tid = threadIdx.x;
    __shared__ float t[64][65];
    for (int i = tid; i < 64 * 64; i += 256) {
        int qi = i >> 6, ei = i & 63;
        int e = e0 + ei;
        t[qi][ei] = (e < En) ? xq[((size_t)(b * Qn + q0 + qi)) * En + e] : 0.f;
    }
    __syncthreads();
    for (int i = tid; i < 64 * 64; i += 256) {
        int ei = i >> 6, qi = i & 63;
        int e = e0 + ei;
        if (e < En)
            xqaT[((size_t)(b * 400 + e)) * Qn + q0 + qi] = f2bf(t[qi][ei]);
    }
}

// ---- k_a_part: K-split partials of a^T = xcT @ s2T^T ----------------------
// grid (13 etiles, 4 ksplit, 16 b); block K-range = ks*512..+512
__global__ __launch_bounds__(256) void k_a_part(const unsigned short* __restrict__ s2T,
                                                const unsigned short* __restrict__ xcT,
                                                float* __restrict__ aP) {
    int mt = blockIdx.x, ks = blockIdx.y, b = blockIdx.z;
    int w = threadIdx.x >> 6, lane = threadIdx.x & 63;
    int lrow = lane & 15, kg = lane >> 4;
    const unsigned short* Ab = xcT + ((size_t)(b * EP + mt * 16 + lrow)) * Cn + ks * 512 + kg * 8;
    const unsigned short* B0 = s2T + ((size_t)(b * Qn + w * 16 + lrow)) * Cn + ks * 512 + kg * 8;
    const unsigned short* B1 = B0 + (size_t)64 * Cn;
    f32x4 acc0 = {}, acc1 = {};
#pragma unroll 4
    for (int kc = 0; kc < 16; ++kc) {
        bf16x8 af = *(const bf16x8*)(Ab + kc * 32);
        bf16x8 b0 = *(const bf16x8*)(B0 + kc * 32);
        bf16x8 b1 = *(const bf16x8*)(B1 + kc * 32);
        acc0 = __builtin_amdgcn_mfma_f32_16x16x32_bf16(af, b0, acc0, 0, 0, 0);
        acc1 = __builtin_amdgcn_mfma_f32_16x16x32_bf16(af, b1, acc1, 0, 0, 0);
    }
    size_t ebase = (size_t)(b * 4 + ks) * EP + mt * 16 + kg * 4;
#pragma unroll
    for (int r = 0; r < 4; ++r) {
        aP[(ebase + r) * Qn + w * 16 + lrow] = acc0[r];
        aP[(ebase + r) * Qn + 64 + w * 16 + lrow] = acc1[r];
    }
}

// ---- k_acomb2: sum 4 partials -> xqaT rows [200,400) ----------------------
__global__ void k_acomb2(const float* __restrict__ aP, unsigned short* __restrict__ xqaT) {
    int gid = blockIdx.x * 256 + threadIdx.x;
    if (gid >= Bn * En * Qn) return;
    int b = gid / (En * Qn), r = gid % (En * Qn);
    int e = r / Qn, q = r % Qn;
    float s = 0.f;
#pragma unroll
    for (int k = 0; k < 4; k++)
        s += aP[((size_t)(b * 4 + k) * EP + e) * Qn + q];
    xqaT[((size_t)(b * 400 + 200 + e)) * Qn + q] = f2bf(s);
}

// ---- k_tail: fused [c2q|q2c] GEMM + feats + projection --------------------
// grid (32 ctiles, 16 b), 512 threads (8 waves), LDS 120.8 KB
__global__ __launch_bounds__(512) void k_tail(const unsigned short* __restrict__ s1,
                                              const unsigned short* __restrict__ xqaT,
                                              const float* __restrict__ xc,
                                              const unsigned short* __restrict__ wpb,
                                              const float* __restrict__ bp,
                                              float* __restrict__ out) {
    int b = blockIdx.y, c0 = blockIdx.x * 64;
    int tid = threadIdx.x;
    int w = tid >> 6, lane = tid & 63;
    int lrow = lane & 15, kg = lane >> 4;
    __shared__ unsigned short s1t[64 * 136];   // pad 128->136: 2-way bank (free)
    __shared__ unsigned short feats[64 * 808]; // [c][f], pad 800->808

    // stage S1 tile [64][128] and feats slot-0 (= bf16(xc tile))
    for (int i = tid; i < 64 * 16; i += 512) {  // 16 x bf16x8 per row
        int row = i >> 4, c8 = i & 15;
        *(bf16x8*)(s1t + row * 136 + c8 * 8) =
            *(const bf16x8*)(s1 + ((size_t)(b * Cn + c0 + row)) * Qn + c8 * 8);
    }
    for (int i = tid; i < 64 * 50; i += 512) {  // 50 float4 per row
        int row = i / 50, e4 = (i % 50) * 4;
        float4 v = *(const float4*)(xc + ((size_t)(b * Cn + c0 + row)) * En + e4);
        ushort4 o;
        o.x = f2bf(v.x); o.y = f2bf(v.y); o.z = f2bf(v.z); o.w = f2bf(v.w);
        *(ushort4*)(feats + row * 808 + e4) = o;
    }
    __syncthreads();

    // phase 1: cq tile in regs. wave w: rows (w&3)*16, col-half (w>>2)
    {
        int rw = (w & 3) * 16, h = w >> 2;
        int j0 = h ? 13 : 0, nj = h ? 12 : 13;
        f32x4 acc[13] = {};
        const unsigned short* Bb = xqaT + ((size_t)b * 400 + lrow) * Qn + kg * 8;
#pragma unroll
        for (int kc = 0; kc < 4; ++kc) {
            bf16x8 af = *(const bf16x8*)(s1t + (rw + lrow) * 136 + kg * 8 + kc * 32);
            for (int j = 0; j < nj; ++j) {
                bf16x8 bfr = *(const bf16x8*)(Bb + (size_t)(j0 + j) * 16 * Qn + kc * 32);
                acc[j] = __builtin_amdgcn_mfma_f32_16x16x32_bf16(af, bfr, acc[j], 0, 0, 0);
            }
        }
        // scatter into feats slots 1..3
        for (int j = 0; j < nj; ++j) {
            int col = (j0 + j) * 16 + lrow;
#pragma unroll
            for (int r = 0; r < 4; ++r) {
                int row = rw + kg * 4 + r;
                float v = acc[j][r];
                if (col < 200) {
                    float x = bf2f(feats[row * 808 + col]);
                    unsigned short vb = f2bf(v);
                    feats[row * 808 + 200 + col] = vb;
                    feats[row * 808 + 400 + col] = f2bf(x * bf2f(vb));
                } else {
                    float x = bf2f(feats[row * 808 + col - 200]);
                    feats[row * 808 + 400 + col] = f2bf(x * v);  // slot3 @600+(col-200)
                }
            }
        }
    }
    __syncthreads();

    // phase 2: out[64][128] = feats @ wp^T. wave w: cols w*16..+16, all rows.
    {
        f32x4 acc[4] = {};
        const unsigned short* Bb = wpb + ((size_t)(w * 16 + lrow)) * Fn + kg * 8;
#pragma unroll 5
        for (int kc = 0; kc < 25; ++kc) {
            bf16x8 bfr = *(const bf16x8*)(Bb + kc * 32);
#pragma unroll
            for (int m = 0; m < 4; ++m) {
                bf16x8 af = *(const bf16x8*)(feats + (m * 16 + lrow) * 808 + kg * 8 + kc * 32);
                acc[m] = __builtin_amdgcn_mfma_f32_16x16x32_bf16(af, bfr, acc[m], 0, 0, 0);
            }
        }
        int o = w * 16 + lrow;
        float bpv = bp[o];
#pragma unroll
        for (int m = 0; m < 4; ++m)
#pragma unroll
            for (int r = 0; r < 4; ++r)
                out[((size_t)(b * Cn + c0 + m * 16 + kg * 4 + r)) * On + o] = acc[m][r] + bpv;
    }
}

extern "C" void kernel_launch(void* const* d_in, const int* in_sizes, int n_in,
                              void* d_out, int out_size, void* d_ws, size_t ws_size,
                              hipStream_t stream) {
    const float* xc = (const float*)d_in[0];
    const float* xq = (const float*)d_in[1];
    const float* wsim = (const float*)d_in[2];
    const float* wp = (const float*)d_in[3];
    const float* bp = (const float*)d_in[4];
    float* out = (float*)d_out;
    float* ws = (float*)d_ws;

    // region 0: scores fp32 (dead after k_s2t); aP aliases it (k_a_part..k_acomb2)
    float* scores = ws;                                            // 4,194,304 f
    float* aP     = ws;                                            // 1,703,936 f (alias)
    // region 1: xc_bf (dead after k_scores_mfma); xcT_bf aliases it
    unsigned short* xc_bf  = (unsigned short*)(ws + 4194304);      // 6,553,600 bf16
    unsigned short* xcT_bf = (unsigned short*)(ws + 4194304);      // 6,815,744 bf16
    unsigned short* s1_bf  = (unsigned short*)(ws + 7602176);      // 4,194,304 bf16
    unsigned short* s2T_bf = (unsigned short*)(ws + 9699328);      // 4,194,304 bf16
    unsigned short* yq_bf  = (unsigned short*)(ws + 11796480);     //   409,600 bf16
    float* s_q    = ws + 12001280;   //  2,048 f
    float* cpM    = ws + 12003328;   // 32,768 f
    float* cpS    = ws + 12036096;   // 32,768 f
    float* colM   = ws + 12068864;   //  2,048 f
    float* colSi  = ws + 12070912;   //  2,048 f
    unsigned short* xqaT_bf = (unsigned short*)(ws + 12072960);    //   819,200 bf16
    unsigned short* wp_bf   = (unsigned short*)(ws + 12482560);    //   102,400 bf16
    // total: 12,533,760 floats = 50.1 MB

    k_yq<<<512, 256, 0, stream>>>(xq, wsim, yq_bf, s_q);
    k_cast_xc<<<6400, 256, 0, stream>>>(xc, xc_bf);
    k_prep_wp<<<100, 256, 0, stream>>>(wp, wp_bf);
    k_scores_mfma<<<dim3(32, 16), 256, 0, stream>>>(xc_bf, yq_bf, s_q, scores, s1_bf);
    k_colpart<<<dim3(16, 16), 128, 0, stream>>>(scores, cpM, cpS);
    k_colcomb<<<16, 128, 0, stream>>>(cpM, cpS, colM, colSi);
    k_s2t<<<dim3(32, 2, 16), 256, 0, stream>>>(scores, colM, colSi, s2T_bf);
    k_xcT<<<dim3(32, 4, 16), 256, 0, stream>>>(xc, xcT_bf);      // xc_bf dead; alias ok
    k_xqT<<<dim3(4, 2, 16), 256, 0, stream>>>(xq, xqaT_bf);
    // scores dead from here; aP aliases region 0
    k_a_part<<<dim3(13, 4, 16), 256, 0, stream>>>(s2T_bf, xcT_bf, aP);
    k_acomb2<<<1600, 256, 0, stream>>>(aP, xqaT_bf);
    k_tail<<<dim3(32, 16), 512, 0, stream>>>(s1_bf, xqaT_bf, xc, wp_bf, bp, out);
}

// Round 5
// 144.069 us; speedup vs baseline: 1.3212x; 1.3212x over previous
//
#include <hip/hip_runtime.h>
#include <hip/hip_bf16.h>

#define Bn 16
#define Cn 2048
#define Qn 128
#define En 200
#define Fn 800
#define On 128
#define EP 208  // padded e-rows for xcT

typedef float f32x4 __attribute__((ext_vector_type(4)));
typedef __bf16 bf16x8 __attribute__((ext_vector_type(8)));

__device__ __forceinline__ unsigned short f2bf(float f) {
    union { float f; unsigned u; } v; v.f = f;
    unsigned r = v.u + 0x7FFF + ((v.u >> 16) & 1);
    return (unsigned short)(r >> 16);
}
__device__ __forceinline__ float bf2f(unsigned short h) {
    union { unsigned u; float f; } v; v.u = (unsigned)h << 16;
    return v.f;
}

// ---- k_yq: yq_bf[b,q,e] = bf16(xq*w3 + w1); s_q[b,q] = dot(xq, w2) --------
__global__ void k_yq(const float* __restrict__ xq, const float* __restrict__ wsim,
                     unsigned short* __restrict__ yqb, float* __restrict__ s_q) {
    int wid = (blockIdx.x * blockDim.x + threadIdx.x) >> 6;
    int lane = threadIdx.x & 63;
    if (wid >= Bn * Qn) return;
    const float* xrow = xq + (size_t)wid * En;
    float s = 0.f;
    for (int e = lane; e < En; e += 64) {
        float x = xrow[e];
        yqb[(size_t)wid * En + e] = f2bf(x * wsim[400 + e] + wsim[e]);
        s += x * wsim[200 + e];
    }
    for (int i = 32; i; i >>= 1) s += __shfl_xor(s, i, 64);
    if (lane == 0) s_q[wid] = s;
}

// ---- k_cast_xc: xc fp32 -> bf16 (same layout) -----------------------------
__global__ void k_cast_xc(const float* __restrict__ xc, unsigned short* __restrict__ xcb) {
    int gid = blockIdx.x * 256 + threadIdx.x;
    int base = gid * 4;
    if (base >= Bn * Cn * En) return;
    float4 v = *(const float4*)(xc + base);
    ushort4 o;
    o.x = f2bf(v.x); o.y = f2bf(v.y); o.z = f2bf(v.z); o.w = f2bf(v.w);
    *(ushort4*)(xcb + base) = o;
}

// ---- k_prep_wp: w_proj -> bf16 [128][800] ---------------------------------
__global__ void k_prep_wp(const float* __restrict__ wp, unsigned short* __restrict__ wpb) {
    int gid = blockIdx.x * 256 + threadIdx.x;
    int base = gid * 4;
    if (base >= On * Fn) return;
    float4 v = *(const float4*)(wp + base);
    ushort4 o;
    o.x = f2bf(v.x); o.y = f2bf(v.y); o.z = f2bf(v.z); o.w = f2bf(v.w);
    *(ushort4*)(wpb + base) = o;
}

// ---- k_scores_mfma: scores = xc_bf @ yq_bf^T + s_q; fused row softmax -----
__global__ __launch_bounds__(256) void k_scores_mfma(const unsigned short* __restrict__ xcb,
                                                     const unsigned short* __restrict__ yqb,
                                                     const float* __restrict__ s_q,
                                                     float* __restrict__ scores,
                                                     unsigned short* __restrict__ s1) {
    int b = blockIdx.y, c0 = blockIdx.x * 64;
    int w = threadIdx.x >> 6, lane = threadIdx.x & 63;
    int lrow = lane & 15, kg = lane >> 4;
    const unsigned short* Ab = xcb + ((size_t)(b * Cn + c0 + w * 16 + lrow)) * En + kg * 8;
    const unsigned short* Bb = yqb + ((size_t)(b * Qn + lrow)) * En + kg * 8;
    f32x4 acc[8] = {};
#pragma unroll
    for (int kc = 0; kc < 7; ++kc) {   // K=200: 6 full chunks + tail (kg==0 only)
        bool valid = (kc < 6) || (kg == 0);
        bf16x8 af = bf16x8{0,0,0,0,0,0,0,0};
        if (valid) af = *(const bf16x8*)(Ab + kc * 32);
#pragma unroll
        for (int j = 0; j < 8; ++j) {
            bf16x8 bfr = bf16x8{0,0,0,0,0,0,0,0};
            if (valid) bfr = *(const bf16x8*)(Bb + (size_t)j * 16 * En + kc * 32);
            acc[j] = __builtin_amdgcn_mfma_f32_16x16x32_bf16(af, bfr, acc[j], 0, 0, 0);
        }
    }
#pragma unroll
    for (int j = 0; j < 8; ++j) {
        float sq = s_q[b * Qn + j * 16 + lrow];
#pragma unroll
        for (int r = 0; r < 4; ++r) acc[j][r] += sq;
    }
    size_t rowbase = (size_t)(b * Cn + c0 + w * 16 + kg * 4);
#pragma unroll
    for (int r = 0; r < 4; ++r)
#pragma unroll
        for (int j = 0; j < 8; ++j)
            scores[(rowbase + r) * Qn + j * 16 + lrow] = acc[j][r];
#pragma unroll
    for (int r = 0; r < 4; ++r) {
        float m = acc[0][r];
#pragma unroll
        for (int j = 1; j < 8; ++j) m = fmaxf(m, acc[j][r]);
        for (int d = 1; d < 16; d <<= 1) m = fmaxf(m, __shfl_xor(m, d, 64));
        float ssum = 0.f;
#pragma unroll
        for (int j = 0; j < 8; ++j) {
            float e_ = __expf(acc[j][r] - m);
            acc[j][r] = e_;
            ssum += e_;
        }
        for (int d = 1; d < 16; d <<= 1) ssum += __shfl_xor(ssum, d, 64);
        float si = 1.f / ssum;
#pragma unroll
        for (int j = 0; j < 8; ++j)
            s1[(rowbase + r) * Qn + j * 16 + lrow] = f2bf(acc[j][r] * si);
    }
}

// ---- k_colpart / k_colcomb ------------------------------------------------
__global__ void k_colpart(const float* __restrict__ scores,
                          float* __restrict__ cpM, float* __restrict__ cpS) {
    int b = blockIdx.y, cch = blockIdx.x;
    int q = threadIdx.x;
    const float* base = scores + (size_t)(b * Cn + cch * 128) * Qn + q;
    float m = -1e30f, s = 0.f;
    for (int c = 0; c < 128; c++) {
        float x = base[(size_t)c * Qn];
        float nm = fmaxf(m, x);
        s = s * __expf(m - nm) + __expf(x - nm);
        m = nm;
    }
    cpM[(b * 16 + cch) * 128 + q] = m;
    cpS[(b * 16 + cch) * 128 + q] = s;
}

__global__ void k_colcomb(const float* __restrict__ cpM, const float* __restrict__ cpS,
                          float* __restrict__ colM, float* __restrict__ colSi) {
    int b = blockIdx.x, q = threadIdx.x;
    float m = -1e30f;
    for (int k = 0; k < 16; k++) m = fmaxf(m, cpM[(b * 16 + k) * 128 + q]);
    float s = 0.f;
    for (int k = 0; k < 16; k++) s += cpS[(b * 16 + k) * 128 + q] * __expf(cpM[(b * 16 + k) * 128 + q] - m);
    colM[b * 128 + q] = m;
    colSi[b * 128 + q] = 1.f / s;
}

// ---- k_s2t: s2T[b][q][c] = bf16(exp(scores[c][q]-colM[q])*colSi[q]) -------
__global__ __launch_bounds__(256) void k_s2t(const float* __restrict__ scores,
                                             const float* __restrict__ colM,
                                             const float* __restrict__ colSi,
                                             unsigned short* __restrict__ s2T) {
    int ct = blockIdx.x, qt = blockIdx.y, b = blockIdx.z;
    int c0 = ct * 64, q0 = qt * 64;
    int tid = threadIdx.x;
    __shared__ float t[64][65];
    for (int i = tid; i < 64 * 64; i += 256) {
        int ci = i >> 6, qi = i & 63;
        t[ci][qi] = scores[((size_t)(b * Cn + c0 + ci)) * Qn + q0 + qi];
    }
    __syncthreads();
    for (int i = tid; i < 64 * 64; i += 256) {
        int qi = i >> 6, ci = i & 63;
        int q = q0 + qi;
        float v = __expf(t[ci][qi] - colM[b * Qn + q]) * colSi[b * Qn + q];
        s2T[((size_t)(b * Qn + q)) * Cn + c0 + ci] = f2bf(v);
    }
}

// ---- k_xcT: xcT[b][e][c] bf16 (rows 200..207 zero) ------------------------
__global__ __launch_bounds__(256) void k_xcT(const float* __restrict__ xc,
                                             unsigned short* __restrict__ xcT) {
    int ct = blockIdx.x, et = blockIdx.y, b = blockIdx.z;
    int c0 = ct * 64, e0 = et * 64;
    int tid = threadIdx.x;
    __shared__ float t[64][65];
    for (int i = tid; i < 64 * 64; i += 256) {
        int ci = i >> 6, ei = i & 63;
        int e = e0 + ei;
        t[ci][ei] = (e < En) ? xc[((size_t)(b * Cn + c0 + ci)) * En + e] : 0.f;
    }
    __syncthreads();
    for (int i = tid; i < 64 * 64; i += 256) {
        int ei = i >> 6, ci = i & 63;
        int e = e0 + ei;
        if (e < EP)
            xcT[((size_t)(b * EP + e)) * Cn + c0 + ci] = f2bf(t[ci][ei]);
    }
}

// ---- k_xqT: xqaT rows [0,200) = xq^T bf16 ---------------------------------
__global__ __launch_bounds__(256) void k_xqT(const float* __restrict__ xq,
                                             unsigned short* __restrict__ xqaT) {
    int et = blockIdx.x, qt = blockIdx.y, b = blockIdx.z;
    int e0 = et * 64, q0 = qt * 64;
    int tid = threadIdx.x;
    __shared__ float t[64][65];
    for (int i = tid; i < 64 * 64; i += 256) {
        int qi = i >> 6, ei = i & 63;
        int e = e0 + ei;
        t[qi][ei] = (e < En) ? xq[((size_t)(b * Qn + q0 + qi)) * En + e] : 0.f;
    }
    __syncthreads();
    for (int i = tid; i < 64 * 64; i += 256) {
        int ei = i >> 6, qi = i & 63;
        int e = e0 + ei;
        if (e < En)
            xqaT[((size_t)(b * 400 + e)) * Qn + q0 + qi] = f2bf(t[qi][ei]);
    }
}

// ---- k_a_part: K-split partials of a^T = xcT @ s2T^T ----------------------
__global__ __launch_bounds__(256) void k_a_part(const unsigned short* __restrict__ s2T,
                                                const unsigned short* __restrict__ xcT,
                                                float* __restrict__ aP) {
    int mt = blockIdx.x, ks = blockIdx.y, b = blockIdx.z;
    int w = threadIdx.x >> 6, lane = threadIdx.x & 63;
    int lrow = lane & 15, kg = lane >> 4;
    const unsigned short* Ab = xcT + ((size_t)(b * EP + mt * 16 + lrow)) * Cn + ks * 512 + kg * 8;
    const unsigned short* B0 = s2T + ((size_t)(b * Qn + w * 16 + lrow)) * Cn + ks * 512 + kg * 8;
    const unsigned short* B1 = B0 + (size_t)64 * Cn;
    f32x4 acc0 = {}, acc1 = {};
#pragma unroll 4
    for (int kc = 0; kc < 16; ++kc) {
        bf16x8 af = *(const bf16x8*)(Ab + kc * 32);
        bf16x8 b0 = *(const bf16x8*)(B0 + kc * 32);
        bf16x8 b1 = *(const bf16x8*)(B1 + kc * 32);
        acc0 = __builtin_amdgcn_mfma_f32_16x16x32_bf16(af, b0, acc0, 0, 0, 0);
        acc1 = __builtin_amdgcn_mfma_f32_16x16x32_bf16(af, b1, acc1, 0, 0, 0);
    }
    size_t ebase = (size_t)(b * 4 + ks) * EP + mt * 16 + kg * 4;
#pragma unroll
    for (int r = 0; r < 4; ++r) {
        aP[(ebase + r) * Qn + w * 16 + lrow] = acc0[r];
        aP[(ebase + r) * Qn + 64 + w * 16 + lrow] = acc1[r];
    }
}

// ---- k_acomb2: sum 4 partials -> xqaT rows [200,400) ----------------------
__global__ void k_acomb2(const float* __restrict__ aP, unsigned short* __restrict__ xqaT) {
    int gid = blockIdx.x * 256 + threadIdx.x;
    if (gid >= Bn * En * Qn) return;
    int b = gid / (En * Qn), r = gid % (En * Qn);
    int e = r / Qn, q = r % Qn;
    float s = 0.f;
#pragma unroll
    for (int k = 0; k < 4; k++)
        s += aP[((size_t)(b * 4 + k) * EP + e) * Qn + q];
    xqaT[((size_t)(b * 400 + 200 + e)) * Qn + q] = f2bf(s);
}

// ---- phase-1 helper: compile-time NJ/J0 so acc[] stays in registers -------
template<int NJ, int J0>
__device__ __forceinline__ void cq_phase(const unsigned short* __restrict__ s1row,
                                         const unsigned short* __restrict__ Bb,
                                         unsigned short* __restrict__ feats,
                                         int rw, int kg, int lrow) {
    f32x4 acc[NJ];
#pragma unroll
    for (int j = 0; j < NJ; ++j) acc[j] = f32x4{0.f, 0.f, 0.f, 0.f};
#pragma unroll
    for (int kc = 0; kc < 4; ++kc) {
        bf16x8 af = *(const bf16x8*)(s1row + kc * 32);
#pragma unroll
        for (int j = 0; j < NJ; ++j) {
            bf16x8 bfr = *(const bf16x8*)(Bb + (size_t)(J0 + j) * 16 * Qn + kc * 32);
            acc[j] = __builtin_amdgcn_mfma_f32_16x16x32_bf16(af, bfr, acc[j], 0, 0, 0);
        }
    }
#pragma unroll
    for (int j = 0; j < NJ; ++j) {
        int col = (J0 + j) * 16 + lrow;
#pragma unroll
        for (int r = 0; r < 4; ++r) {
            int row = rw + kg * 4 + r;
            float v = acc[j][r];
            if (col < 200) {
                float x = bf2f(feats[row * 808 + col]);
                unsigned short vb = f2bf(v);
                feats[row * 808 + 200 + col] = vb;
                feats[row * 808 + 400 + col] = f2bf(x * bf2f(vb));
            } else {
                float x = bf2f(feats[row * 808 + col - 200]);
                feats[row * 808 + 400 + col] = f2bf(x * v);  // slot3 @ 600+(col-200)
            }
        }
    }
}

// ---- k_tail: fused [c2q|q2c] GEMM + feats + projection --------------------
// grid (32 ctiles, 16 b), 512 threads (8 waves), LDS 120.8 KB
__global__ __launch_bounds__(512) void k_tail(const unsigned short* __restrict__ s1,
                                              const unsigned short* __restrict__ xqaT,
                                              const float* __restrict__ xc,
                                              const unsigned short* __restrict__ wpb,
                                              const float* __restrict__ bp,
                                              float* __restrict__ out) {
    int b = blockIdx.y, c0 = blockIdx.x * 64;
    int tid = threadIdx.x;
    int w = tid >> 6, lane = tid & 63;
    int lrow = lane & 15, kg = lane >> 4;
    __shared__ unsigned short s1t[64 * 136];   // pad 128->136: 2-way bank (free)
    __shared__ unsigned short feats[64 * 808]; // [c][f], pad 800->808

    // stage S1 tile [64][128] and feats slot-0 (= bf16(xc tile))
    for (int i = tid; i < 64 * 16; i += 512) {
        int row = i >> 4, c8 = i & 15;
        *(bf16x8*)(s1t + row * 136 + c8 * 8) =
            *(const bf16x8*)(s1 + ((size_t)(b * Cn + c0 + row)) * Qn + c8 * 8);
    }
    for (int i = tid; i < 64 * 50; i += 512) {
        int row = i / 50, e4 = (i % 50) * 4;
        float4 v = *(const float4*)(xc + ((size_t)(b * Cn + c0 + row)) * En + e4);
        ushort4 o;
        o.x = f2bf(v.x); o.y = f2bf(v.y); o.z = f2bf(v.z); o.w = f2bf(v.w);
        *(ushort4*)(feats + row * 808 + e4) = o;
    }
    __syncthreads();

    // phase 1: cq tile in regs. wave w: rows (w&3)*16, col-half (w>>2)
    {
        int rw = (w & 3) * 16;
        const unsigned short* s1row = s1t + (rw + lrow) * 136 + kg * 8;
        const unsigned short* Bb = xqaT + ((size_t)b * 400 + lrow) * Qn + kg * 8;
        if ((w >> 2) == 0) cq_phase<13, 0>(s1row, Bb, feats, rw, kg, lrow);
        else               cq_phase<12, 13>(s1row, Bb, feats, rw, kg, lrow);
    }
    __syncthreads();

    // phase 2: out[64][128] = feats @ wp^T. wave w: cols w*16..+16, all rows.
    {
        f32x4 acc[4] = {};
        const unsigned short* Bb = wpb + ((size_t)(w * 16 + lrow)) * Fn + kg * 8;
#pragma unroll 5
        for (int kc = 0; kc < 25; ++kc) {
            bf16x8 bfr = *(const bf16x8*)(Bb + kc * 32);
#pragma unroll
            for (int m = 0; m < 4; ++m) {
                bf16x8 af = *(const bf16x8*)(feats + (m * 16 + lrow) * 808 + kg * 8 + kc * 32);
                acc[m] = __builtin_amdgcn_mfma_f32_16x16x32_bf16(af, bfr, acc[m], 0, 0, 0);
            }
        }
        int o = w * 16 + lrow;
        float bpv = bp[o];
#pragma unroll
        for (int m = 0; m < 4; ++m)
#pragma unroll
            for (int r = 0; r < 4; ++r)
                out[((size_t)(b * Cn + c0 + m * 16 + kg * 4 + r)) * On + o] = acc[m][r] + bpv;
    }
}

extern "C" void kernel_launch(void* const* d_in, const int* in_sizes, int n_in,
                              void* d_out, int out_size, void* d_ws, size_t ws_size,
                              hipStream_t stream) {
    const float* xc = (const float*)d_in[0];
    const float* xq = (const float*)d_in[1];
    const float* wsim = (const float*)d_in[2];
    const float* wp = (const float*)d_in[3];
    const float* bp = (const float*)d_in[4];
    float* out = (float*)d_out;
    float* ws = (float*)d_ws;

    // region 0: scores fp32 (dead after k_s2t); aP aliases it (k_a_part..k_acomb2)
    float* scores = ws;                                            // 4,194,304 f
    float* aP     = ws;                                            // 1,703,936 f (alias)
    // region 1: xc_bf (dead after k_scores_mfma); xcT_bf aliases it
    unsigned short* xc_bf  = (unsigned short*)(ws + 4194304);      // 6,553,600 bf16
    unsigned short* xcT_bf = (unsigned short*)(ws + 4194304);      // 6,815,744 bf16
    unsigned short* s1_bf  = (unsigned short*)(ws + 7602176);      // 4,194,304 bf16
    unsigned short* s2T_bf = (unsigned short*)(ws + 9699328);      // 4,194,304 bf16
    unsigned short* yq_bf  = (unsigned short*)(ws + 11796480);     //   409,600 bf16
    float* s_q    = ws + 12001280;   //  2,048 f
    float* cpM    = ws + 12003328;   // 32,768 f
    float* cpS    = ws + 12036096;   // 32,768 f
    float* colM   = ws + 12068864;   //  2,048 f
    float* colSi  = ws + 12070912;   //  2,048 f
    unsigned short* xqaT_bf = (unsigned short*)(ws + 12072960);    //   819,200 bf16
    unsigned short* wp_bf   = (unsigned short*)(ws + 12482560);    //   102,400 bf16
    // total: 12,533,760 floats = 50.1 MB

    k_yq<<<512, 256, 0, stream>>>(xq, wsim, yq_bf, s_q);
    k_cast_xc<<<6400, 256, 0, stream>>>(xc, xc_bf);
    k_prep_wp<<<100, 256, 0, stream>>>(wp, wp_bf);
    k_scores_mfma<<<dim3(32, 16), 256, 0, stream>>>(xc_bf, yq_bf, s_q, scores, s1_bf);
    k_colpart<<<dim3(16, 16), 128, 0, stream>>>(scores, cpM, cpS);
    k_colcomb<<<16, 128, 0, stream>>>(cpM, cpS, colM, colSi);
    k_s2t<<<dim3(32, 2, 16), 256, 0, stream>>>(scores, colM, colSi, s2T_bf);
    k_xcT<<<dim3(32, 4, 16), 256, 0, stream>>>(xc, xcT_bf);      // xc_bf dead; alias ok
    k_xqT<<<dim3(4, 2, 16), 256, 0, stream>>>(xq, xqaT_bf);
    // scores dead from here; aP aliases region 0
    k_a_part<<<dim3(13, 4, 16), 256, 0, stream>>>(s2T_bf, xcT_bf, aP);
    k_acomb2<<<1600, 256, 0, stream>>>(aP, xqaT_bf);
    k_tail<<<dim3(32, 16), 512, 0, stream>>>(s1_bf, xqaT_bf, xc, wp_bf, bp, out);
}

// Round 6
// 129.810 us; speedup vs baseline: 1.4663x; 1.1098x over previous
//
#include <hip/hip_runtime.h>
#include <hip/hip_bf16.h>

#define Bn 16
#define Cn 2048
#define Qn 128
#define En 200
#define Fn 800
#define On 128
#define EP 208  // padded e-rows for xcT

typedef float f32x4 __attribute__((ext_vector_type(4)));
typedef __bf16 bf16x8 __attribute__((ext_vector_type(8)));

__device__ __forceinline__ unsigned short f2bf(float f) {
    union { float f; unsigned u; } v; v.f = f;
    unsigned r = v.u + 0x7FFF + ((v.u >> 16) & 1);
    return (unsigned short)(r >> 16);
}
__device__ __forceinline__ float bf2f(unsigned short h) {
    union { unsigned u; float f; } v; v.u = (unsigned)h << 16;
    return v.f;
}

// ---- k_yq: yq_bf[b,q,e] = bf16(xq*w3 + w1); s_q[b,q] = dot(xq, w2) --------
__global__ void k_yq(const float* __restrict__ xq, const float* __restrict__ wsim,
                     unsigned short* __restrict__ yqb, float* __restrict__ s_q) {
    int wid = (blockIdx.x * blockDim.x + threadIdx.x) >> 6;
    int lane = threadIdx.x & 63;
    if (wid >= Bn * Qn) return;
    const float* xrow = xq + (size_t)wid * En;
    float s = 0.f;
    for (int e = lane; e < En; e += 64) {
        float x = xrow[e];
        yqb[(size_t)wid * En + e] = f2bf(x * wsim[400 + e] + wsim[e]);
        s += x * wsim[200 + e];
    }
    for (int i = 32; i; i >>= 1) s += __shfl_xor(s, i, 64);
    if (lane == 0) s_q[wid] = s;
}

// ---- k_cast_xc: xc fp32 -> bf16 (same layout) -----------------------------
__global__ void k_cast_xc(const float* __restrict__ xc, unsigned short* __restrict__ xcb) {
    int gid = blockIdx.x * 256 + threadIdx.x;
    int base = gid * 4;
    if (base >= Bn * Cn * En) return;
    float4 v = *(const float4*)(xc + base);
    ushort4 o;
    o.x = f2bf(v.x); o.y = f2bf(v.y); o.z = f2bf(v.z); o.w = f2bf(v.w);
    *(ushort4*)(xcb + base) = o;
}

// ---- k_prep_wp: w_proj -> bf16 [128][800] ---------------------------------
__global__ void k_prep_wp(const float* __restrict__ wp, unsigned short* __restrict__ wpb) {
    int gid = blockIdx.x * 256 + threadIdx.x;
    int base = gid * 4;
    if (base >= On * Fn) return;
    float4 v = *(const float4*)(wp + base);
    ushort4 o;
    o.x = f2bf(v.x); o.y = f2bf(v.y); o.z = f2bf(v.z); o.w = f2bf(v.w);
    *(ushort4*)(wpb + base) = o;
}

// ---- k_scores_mfma: scores GEMM + fused row softmax (s1) + block-local ----
// col stats (cpM/cpS) + transposed unnormalized-exp ET[b][q][c] (bf16)
__global__ __launch_bounds__(256) void k_scores_mfma(const unsigned short* __restrict__ xcb,
                                                     const unsigned short* __restrict__ yqb,
                                                     const float* __restrict__ s_q,
                                                     unsigned short* __restrict__ ET,
                                                     unsigned short* __restrict__ s1,
                                                     float* __restrict__ cpM,
                                                     float* __restrict__ cpS) {
    int b = blockIdx.y, blk = blockIdx.x, c0 = blk * 64;
    int w = threadIdx.x >> 6, lane = threadIdx.x & 63;
    int lrow = lane & 15, kg = lane >> 4;
    __shared__ float colm4[4][128];
    __shared__ float cols4[4][128];
    const unsigned short* Ab = xcb + ((size_t)(b * Cn + c0 + w * 16 + lrow)) * En + kg * 8;
    const unsigned short* Bb = yqb + ((size_t)(b * Qn + lrow)) * En + kg * 8;
    f32x4 acc[8] = {};
#pragma unroll
    for (int kc = 0; kc < 7; ++kc) {   // K=200: 6 full chunks + tail (kg==0 only)
        bool valid = (kc < 6) || (kg == 0);
        bf16x8 af = bf16x8{0,0,0,0,0,0,0,0};
        if (valid) af = *(const bf16x8*)(Ab + kc * 32);
#pragma unroll
        for (int j = 0; j < 8; ++j) {
            bf16x8 bfr = bf16x8{0,0,0,0,0,0,0,0};
            if (valid) bfr = *(const bf16x8*)(Bb + (size_t)j * 16 * En + kc * 32);
            acc[j] = __builtin_amdgcn_mfma_f32_16x16x32_bf16(af, bfr, acc[j], 0, 0, 0);
        }
    }
#pragma unroll
    for (int j = 0; j < 8; ++j) {
        float sq = s_q[b * Qn + j * 16 + lrow];
#pragma unroll
        for (int r = 0; r < 4; ++r) acc[j][r] += sq;
    }
    // ---- column (axis c) partial stats over this block's 64 rows ----------
    float lm[8], ls[8];
#pragma unroll
    for (int j = 0; j < 8; ++j) {
        float m = fmaxf(fmaxf(acc[j][0], acc[j][1]), fmaxf(acc[j][2], acc[j][3]));
        m = fmaxf(m, __shfl_xor(m, 16, 64));
        m = fmaxf(m, __shfl_xor(m, 32, 64));
        lm[j] = m;
        float s = __expf(acc[j][0] - m) + __expf(acc[j][1] - m)
                + __expf(acc[j][2] - m) + __expf(acc[j][3] - m);
        s += __shfl_xor(s, 16, 64);
        s += __shfl_xor(s, 32, 64);
        ls[j] = s;
    }
    if (kg == 0) {
#pragma unroll
        for (int j = 0; j < 8; ++j) {
            colm4[w][j * 16 + lrow] = lm[j];
            cols4[w][j * 16 + lrow] = ls[j];
        }
    }
    __syncthreads();
    float mb[8];
#pragma unroll
    for (int j = 0; j < 8; ++j) {
        int q = j * 16 + lrow;
        float m = fmaxf(fmaxf(colm4[0][q], colm4[1][q]), fmaxf(colm4[2][q], colm4[3][q]));
        mb[j] = m;
        if (w == 0 && kg == 0) {
            float sb = cols4[0][q] * __expf(colm4[0][q] - m)
                     + cols4[1][q] * __expf(colm4[1][q] - m)
                     + cols4[2][q] * __expf(colm4[2][q] - m)
                     + cols4[3][q] * __expf(colm4[3][q] - m);
            cpM[(b * 32 + blk) * 128 + q] = m;
            cpS[(b * 32 + blk) * 128 + q] = sb;
        }
    }
    // ---- ET write (transposed): ET[b][q][c0 + w*16 + kg*4 + r] ------------
#pragma unroll
    for (int j = 0; j < 8; ++j) {
        int q = j * 16 + lrow;
        ushort4 o;
        o.x = f2bf(__expf(acc[j][0] - mb[j]));
        o.y = f2bf(__expf(acc[j][1] - mb[j]));
        o.z = f2bf(__expf(acc[j][2] - mb[j]));
        o.w = f2bf(__expf(acc[j][3] - mb[j]));
        *(ushort4*)(ET + ((size_t)(b * Qn + q)) * Cn + c0 + w * 16 + kg * 4) = o;
    }
    // ---- row softmax -> s1 -------------------------------------------------
    size_t rowbase = (size_t)(b * Cn + c0 + w * 16 + kg * 4);
#pragma unroll
    for (int r = 0; r < 4; ++r) {
        float m = acc[0][r];
#pragma unroll
        for (int j = 1; j < 8; ++j) m = fmaxf(m, acc[j][r]);
        for (int d = 1; d < 16; d <<= 1) m = fmaxf(m, __shfl_xor(m, d, 64));
        float ssum = 0.f;
        float e[8];
#pragma unroll
        for (int j = 0; j < 8; ++j) {
            e[j] = __expf(acc[j][r] - m);
            ssum += e[j];
        }
        for (int d = 1; d < 16; d <<= 1) ssum += __shfl_xor(ssum, d, 64);
        float si = 1.f / ssum;
#pragma unroll
        for (int j = 0; j < 8; ++j)
            s1[(rowbase + r) * Qn + j * 16 + lrow] = f2bf(e[j] * si);
    }
}

// ---- k_colcomb: combine 32 block partials -> colM, colSi ------------------
__global__ void k_colcomb(const float* __restrict__ cpM, const float* __restrict__ cpS,
                          float* __restrict__ colM, float* __restrict__ colSi) {
    int b = blockIdx.x, q = threadIdx.x;
    float m = -1e30f;
    for (int k = 0; k < 32; k++) m = fmaxf(m, cpM[(b * 32 + k) * 128 + q]);
    float s = 0.f;
    for (int k = 0; k < 32; k++) s += cpS[(b * 32 + k) * 128 + q] * __expf(cpM[(b * 32 + k) * 128 + q] - m);
    colM[b * 128 + q] = m;
    colSi[b * 128 + q] = 1.f / s;
}

// ---- k_s2corr: in-place ET[b][q][c] *= exp(cpM[b][c/64][q]-colM)*colSi ----
__global__ void k_s2corr(unsigned short* __restrict__ ET, const float* __restrict__ cpM,
                         const float* __restrict__ colM, const float* __restrict__ colSi) {
    int gid = blockIdx.x * 256 + threadIdx.x;   // one per 8 elems: 524288 total
    int row = gid >> 8;                          // b*128 + q
    int b = row >> 7, q = row & 127;
    int cc = (gid & 255) << 3;
    float corr = __expf(cpM[(b * 32 + (cc >> 6)) * 128 + q] - colM[row]) * colSi[row];
    unsigned short* p = ET + (size_t)row * Cn + cc;
    ushort4 v0 = *(ushort4*)p, v1 = *(ushort4*)(p + 4);
    ushort4 o0, o1;
    o0.x = f2bf(bf2f(v0.x) * corr); o0.y = f2bf(bf2f(v0.y) * corr);
    o0.z = f2bf(bf2f(v0.z) * corr); o0.w = f2bf(bf2f(v0.w) * corr);
    o1.x = f2bf(bf2f(v1.x) * corr); o1.y = f2bf(bf2f(v1.y) * corr);
    o1.z = f2bf(bf2f(v1.z) * corr); o1.w = f2bf(bf2f(v1.w) * corr);
    *(ushort4*)p = o0; *(ushort4*)(p + 4) = o1;
}

// ---- k_xcT: xcT[b][e][c] bf16 (rows 200..207 zero) ------------------------
__global__ __launch_bounds__(256) void k_xcT(const float* __restrict__ xc,
                                             unsigned short* __restrict__ xcT) {
    int ct = blockIdx.x, et = blockIdx.y, b = blockIdx.z;
    int c0 = ct * 64, e0 = et * 64;
    int tid = threadIdx.x;
    __shared__ float t[64][65];
    for (int i = tid; i < 64 * 64; i += 256) {
        int ci = i >> 6, ei = i & 63;
        int e = e0 + ei;
        t[ci][ei] = (e < En) ? xc[((size_t)(b * Cn + c0 + ci)) * En + e] : 0.f;
    }
    __syncthreads();
    for (int i = tid; i < 64 * 64; i += 256) {
        int ei = i >> 6, ci = i & 63;
        int e = e0 + ei;
        if (e < EP)
            xcT[((size_t)(b * EP + e)) * Cn + c0 + ci] = f2bf(t[ci][ei]);
    }
}

// ---- k_xqT: xqaT rows [0,200) = xq^T bf16 ---------------------------------
__global__ __launch_bounds__(256) void k_xqT(const float* __restrict__ xq,
                                             unsigned short* __restrict__ xqaT) {
    int et = blockIdx.x, qt = blockIdx.y, b = blockIdx.z;
    int e0 = et * 64, q0 = qt * 64;
    int tid = threadIdx.x;
    __shared__ float t[64][65];
    for (int i = tid; i < 64 * 64; i += 256) {
        int qi = i >> 6, ei = i & 63;
        int e = e0 + ei;
        t[qi][ei] = (e < En) ? xq[((size_t)(b * Qn + q0 + qi)) * En + e] : 0.f;
    }
    __syncthreads();
    for (int i = tid; i < 64 * 64; i += 256) {
        int ei = i >> 6, qi = i & 63;
        int e = e0 + ei;
        if (e < En)
            xqaT[((size_t)(b * 400 + e)) * Qn + q0 + qi] = f2bf(t[qi][ei]);
    }
}

// ---- k_a_part: K-split partials of a^T = xcT @ s2T^T ----------------------
__global__ __launch_bounds__(256) void k_a_part(const unsigned short* __restrict__ s2T,
                                                const unsigned short* __restrict__ xcT,
                                                float* __restrict__ aP) {
    int mt = blockIdx.x, ks = blockIdx.y, b = blockIdx.z;
    int w = threadIdx.x >> 6, lane = threadIdx.x & 63;
    int lrow = lane & 15, kg = lane >> 4;
    const unsigned short* Ab = xcT + ((size_t)(b * EP + mt * 16 + lrow)) * Cn + ks * 512 + kg * 8;
    const unsigned short* B0 = s2T + ((size_t)(b * Qn + w * 16 + lrow)) * Cn + ks * 512 + kg * 8;
    const unsigned short* B1 = B0 + (size_t)64 * Cn;
    f32x4 acc0 = {}, acc1 = {};
#pragma unroll 4
    for (int kc = 0; kc < 16; ++kc) {
        bf16x8 af = *(const bf16x8*)(Ab + kc * 32);
        bf16x8 b0 = *(const bf16x8*)(B0 + kc * 32);
        bf16x8 b1 = *(const bf16x8*)(B1 + kc * 32);
        acc0 = __builtin_amdgcn_mfma_f32_16x16x32_bf16(af, b0, acc0, 0, 0, 0);
        acc1 = __builtin_amdgcn_mfma_f32_16x16x32_bf16(af, b1, acc1, 0, 0, 0);
    }
    size_t ebase = (size_t)(b * 4 + ks) * EP + mt * 16 + kg * 4;
#pragma unroll
    for (int r = 0; r < 4; ++r) {
        aP[(ebase + r) * Qn + w * 16 + lrow] = acc0[r];
        aP[(ebase + r) * Qn + 64 + w * 16 + lrow] = acc1[r];
    }
}

// ---- k_acomb2: sum 4 partials -> xqaT rows [200,400) ----------------------
__global__ void k_acomb2(const float* __restrict__ aP, unsigned short* __restrict__ xqaT) {
    int gid = blockIdx.x * 256 + threadIdx.x;
    if (gid >= Bn * En * Qn) return;
    int b = gid / (En * Qn), r = gid % (En * Qn);
    int e = r / Qn, q = r % Qn;
    float s = 0.f;
#pragma unroll
    for (int k = 0; k < 4; k++)
        s += aP[((size_t)(b * 4 + k) * EP + e) * Qn + q];
    xqaT[((size_t)(b * 400 + 200 + e)) * Qn + q] = f2bf(s);
}

// ---- phase-1 helper: compile-time NJ/J0 so acc[] stays in registers -------
template<int NJ, int J0>
__device__ __forceinline__ void cq_phase(const unsigned short* __restrict__ s1row,
                                         const unsigned short* __restrict__ Bb,
                                         unsigned short* __restrict__ feats,
                                         int rw, int kg, int lrow) {
    f32x4 acc[NJ];
#pragma unroll
    for (int j = 0; j < NJ; ++j) acc[j] = f32x4{0.f, 0.f, 0.f, 0.f};
#pragma unroll
    for (int kc = 0; kc < 4; ++kc) {
        bf16x8 af = *(const bf16x8*)(s1row + kc * 32);
#pragma unroll
        for (int j = 0; j < NJ; ++j) {
            bf16x8 bfr = *(const bf16x8*)(Bb + (size_t)(J0 + j) * 16 * Qn + kc * 32);
            acc[j] = __builtin_amdgcn_mfma_f32_16x16x32_bf16(af, bfr, acc[j], 0, 0, 0);
        }
    }
#pragma unroll
    for (int j = 0; j < NJ; ++j) {
        int col = (J0 + j) * 16 + lrow;
#pragma unroll
        for (int r = 0; r < 4; ++r) {
            int row = rw + kg * 4 + r;
            float v = acc[j][r];
            if (col < 200) {
                float x = bf2f(feats[row * 808 + col]);
                unsigned short vb = f2bf(v);
                feats[row * 808 + 200 + col] = vb;
                feats[row * 808 + 400 + col] = f2bf(x * bf2f(vb));
            } else {
                float x = bf2f(feats[row * 808 + col - 200]);
                feats[row * 808 + 400 + col] = f2bf(x * v);  // slot3 @ 600+(col-200)
            }
        }
    }
}

// ---- k_tail: fused [c2q|q2c] GEMM + feats + projection, 32-row tiles ------
// grid (64 ctiles, 16 b), 512 threads (8 waves), LDS 60.4 KB -> 2 blocks/CU
__global__ __launch_bounds__(512) void k_tail(const unsigned short* __restrict__ s1,
                                              const unsigned short* __restrict__ xqaT,
                                              const float* __restrict__ xc,
                                              const unsigned short* __restrict__ wpb,
                                              const float* __restrict__ bp,
                                              float* __restrict__ out) {
    int b = blockIdx.y, c0 = blockIdx.x * 32;
    int tid = threadIdx.x;
    int w = tid >> 6, lane = tid & 63;
    int lrow = lane & 15, kg = lane >> 4;
    __shared__ unsigned short s1t[32 * 136];   // pad 128->136: 2-way bank (free)
    __shared__ unsigned short feats[32 * 808]; // [c][f], pad 800->808

    // stage S1 tile [32][128] and feats slot-0 (= bf16(xc tile))
    for (int i = tid; i < 32 * 16; i += 512) {
        int row = i >> 4, c8 = i & 15;
        *(bf16x8*)(s1t + row * 136 + c8 * 8) =
            *(const bf16x8*)(s1 + ((size_t)(b * Cn + c0 + row)) * Qn + c8 * 8);
    }
    for (int i = tid; i < 32 * 50; i += 512) {
        int row = i / 50, e4 = (i % 50) * 4;
        float4 v = *(const float4*)(xc + ((size_t)(b * Cn + c0 + row)) * En + e4);
        ushort4 o;
        o.x = f2bf(v.x); o.y = f2bf(v.y); o.z = f2bf(v.z); o.w = f2bf(v.w);
        *(ushort4*)(feats + row * 808 + e4) = o;
    }
    __syncthreads();

    // phase 1: wave w: rows (w&1)*16, col-quarter (w>>1)
    {
        int rw = (w & 1) * 16;
        const unsigned short* s1row = s1t + (rw + lrow) * 136 + kg * 8;
        const unsigned short* Bb = xqaT + ((size_t)b * 400 + lrow) * Qn + kg * 8;
        int quarter = w >> 1;
        if (quarter == 0)      cq_phase<7, 0>(s1row, Bb, feats, rw, kg, lrow);
        else if (quarter == 1) cq_phase<6, 7>(s1row, Bb, feats, rw, kg, lrow);
        else if (quarter == 2) cq_phase<6, 13>(s1row, Bb, feats, rw, kg, lrow);
        else                   cq_phase<6, 19>(s1row, Bb, feats, rw, kg, lrow);
    }
    __syncthreads();

    // phase 2: out[32][128] = feats @ wp^T. wave w: cols w*16..+16, rows m*16.
    {
        f32x4 acc[2] = {};
        const unsigned short* Bb = wpb + ((size_t)(w * 16 + lrow)) * Fn + kg * 8;
#pragma unroll 5
        for (int kc = 0; kc < 25; ++kc) {
            bf16x8 bfr = *(const bf16x8*)(Bb + kc * 32);
#pragma unroll
            for (int m = 0; m < 2; ++m) {
                bf16x8 af = *(const bf16x8*)(feats + (m * 16 + lrow) * 808 + kg * 8 + kc * 32);
                acc[m] = __builtin_amdgcn_mfma_f32_16x16x32_bf16(af, bfr, acc[m], 0, 0, 0);
            }
        }
        int o = w * 16 + lrow;
        float bpv = bp[o];
#pragma unroll
        for (int m = 0; m < 2; ++m)
#pragma unroll
            for (int r = 0; r < 4; ++r)
                out[((size_t)(b * Cn + c0 + m * 16 + kg * 4 + r)) * On + o] = acc[m][r] + bpv;
    }
}

extern "C" void kernel_launch(void* const* d_in, const int* in_sizes, int n_in,
                              void* d_out, int out_size, void* d_ws, size_t ws_size,
                              hipStream_t stream) {
    const float* xc = (const float*)d_in[0];
    const float* xq = (const float*)d_in[1];
    const float* wsim = (const float*)d_in[2];
    const float* wp = (const float*)d_in[3];
    const float* bp = (const float*)d_in[4];
    float* out = (float*)d_out;
    float* ws = (float*)d_ws;

    unsigned short* ET_s2T = (unsigned short*)ws;                  // 4,194,304 bf16 (E^T, scaled in place -> s2T)
    unsigned short* s1_bf  = (unsigned short*)(ws + 2097152);      // 4,194,304 bf16
    // xc_bf dead after k_scores_mfma; aP aliases it
    unsigned short* xc_bf  = (unsigned short*)(ws + 4194304);      // 6,553,600 bf16
    float* aP              = ws + 4194304;                         // 1,703,936 f (alias)
    unsigned short* xcT_bf = (unsigned short*)(ws + 7471104);      // 6,815,744 bf16
    unsigned short* yq_bf  = (unsigned short*)(ws + 10878976);     //   409,600 bf16
    unsigned short* xqaT_bf= (unsigned short*)(ws + 11083776);     //   819,200 bf16
    unsigned short* wp_bf  = (unsigned short*)(ws + 11493376);     //   102,400 bf16
    float* s_q   = ws + 11544576;   //  2,048 f
    float* cpM   = ws + 11546624;   // 65,536 f  [b][32][128]
    float* cpS   = ws + 11612160;   // 65,536 f
    float* colM  = ws + 11677696;   //  2,048 f
    float* colSi = ws + 11679744;   //  2,048 f
    // total: 11,681,792 floats = 46.7 MB

    k_yq<<<512, 256, 0, stream>>>(xq, wsim, yq_bf, s_q);
    k_cast_xc<<<6400, 256, 0, stream>>>(xc, xc_bf);
    k_prep_wp<<<100, 256, 0, stream>>>(wp, wp_bf);
    k_scores_mfma<<<dim3(32, 16), 256, 0, stream>>>(xc_bf, yq_bf, s_q, ET_s2T, s1_bf, cpM, cpS);
    k_colcomb<<<16, 128, 0, stream>>>(cpM, cpS, colM, colSi);
    k_s2corr<<<2048, 256, 0, stream>>>(ET_s2T, cpM, colM, colSi);
    k_xcT<<<dim3(32, 4, 16), 256, 0, stream>>>(xc, xcT_bf);
    k_xqT<<<dim3(4, 2, 16), 256, 0, stream>>>(xq, xqaT_bf);
    // xc_bf dead from here; aP aliases it
    k_a_part<<<dim3(13, 4, 16), 256, 0, stream>>>(ET_s2T, xcT_bf, aP);
    k_acomb2<<<1600, 256, 0, stream>>>(aP, xqaT_bf);
    k_tail<<<dim3(64, 16), 512, 0, stream>>>(s1_bf, xqaT_bf, xc, wp_bf, bp, out);
}

// Round 7
// 123.016 us; speedup vs baseline: 1.5473x; 1.0552x over previous
//
#include <hip/hip_runtime.h>
#include <hip/hip_bf16.h>

#define Bn 16
#define Cn 2048
#define Qn 128
#define En 200
#define Fn 800
#define On 128
#define EP 208  // padded e-rows for xcT

typedef float f32x4 __attribute__((ext_vector_type(4)));
typedef __bf16 bf16x8 __attribute__((ext_vector_type(8)));

__device__ __forceinline__ unsigned short f2bf(float f) {
    union { float f; unsigned u; } v; v.f = f;
    unsigned r = v.u + 0x7FFF + ((v.u >> 16) & 1);
    return (unsigned short)(r >> 16);
}
__device__ __forceinline__ float bf2f(unsigned short h) {
    union { unsigned u; float f; } v; v.u = (unsigned)h << 16;
    return v.f;
}
__device__ __forceinline__ bf16x8 mul8(bf16x8 a, bf16x8 b) {
    bf16x8 o;
#pragma unroll
    for (int k = 0; k < 8; ++k) o[k] = (__bf16)((float)a[k] * (float)b[k]);
    return o;
}

// ---- k_yq: yq_bf[b,q,e] = bf16(xq*w3 + w1); s_q[b,q] = dot(xq, w2) --------
__global__ void k_yq(const float* __restrict__ xq, const float* __restrict__ wsim,
                     unsigned short* __restrict__ yqb, float* __restrict__ s_q) {
    int wid = (blockIdx.x * blockDim.x + threadIdx.x) >> 6;
    int lane = threadIdx.x & 63;
    if (wid >= Bn * Qn) return;
    const float* xrow = xq + (size_t)wid * En;
    float s = 0.f;
    for (int e = lane; e < En; e += 64) {
        float x = xrow[e];
        yqb[(size_t)wid * En + e] = f2bf(x * wsim[400 + e] + wsim[e]);
        s += x * wsim[200 + e];
    }
    for (int i = 32; i; i >>= 1) s += __shfl_xor(s, i, 64);
    if (lane == 0) s_q[wid] = s;
}

// ---- k_prep_xc: one pass over fp32 xc -> xc_bf (row-major) + xcT (trans) --
__global__ __launch_bounds__(256) void k_prep_xc(const float* __restrict__ xc,
                                                 unsigned short* __restrict__ xcb,
                                                 unsigned short* __restrict__ xcT) {
    int ct = blockIdx.x, et = blockIdx.y, b = blockIdx.z;   // 32, 4, 16
    int c0 = ct * 64, e0 = et * 64;
    int tid = threadIdx.x;
    __shared__ float t[64][65];
    for (int i = tid; i < 64 * 64; i += 256) {
        int ci = i >> 6, ei = i & 63;
        int e = e0 + ei;
        t[ci][ei] = (e < En) ? xc[((size_t)(b * Cn + c0 + ci)) * En + e] : 0.f;
    }
    __syncthreads();
    // row-major bf16 (ushort4 chunks)
    for (int i = tid; i < 64 * 16; i += 256) {
        int ci = i >> 4, g4 = (i & 15) * 4;
        int e = e0 + g4;
        if (e + 3 < En) {
            ushort4 o;
            o.x = f2bf(t[ci][g4]); o.y = f2bf(t[ci][g4 + 1]);
            o.z = f2bf(t[ci][g4 + 2]); o.w = f2bf(t[ci][g4 + 3]);
            *(ushort4*)(xcb + ((size_t)(b * Cn + c0 + ci)) * En + e) = o;
        }
    }
    // transposed bf16 (rows 200..207 zero)
    for (int i = tid; i < 64 * 64; i += 256) {
        int ei = i >> 6, ci = i & 63;
        int e = e0 + ei;
        if (e < EP)
            xcT[((size_t)(b * EP + e)) * Cn + c0 + ci] = f2bf(t[ci][ei]);
    }
}

// ---- k_prep_wp: w_proj -> bf16 [128][800] ---------------------------------
__global__ void k_prep_wp(const float* __restrict__ wp, unsigned short* __restrict__ wpb) {
    int gid = blockIdx.x * 256 + threadIdx.x;
    int base = gid * 4;
    if (base >= On * Fn) return;
    float4 v = *(const float4*)(wp + base);
    ushort4 o;
    o.x = f2bf(v.x); o.y = f2bf(v.y); o.z = f2bf(v.z); o.w = f2bf(v.w);
    *(ushort4*)(wpb + base) = o;
}

// ---- k_scores_mfma: scores GEMM + fused row softmax (s1) + block-local ----
// col stats (cpM/cpS) + transposed unnormalized-exp ET[b][q][c] (bf16)
__global__ __launch_bounds__(256) void k_scores_mfma(const unsigned short* __restrict__ xcb,
                                                     const unsigned short* __restrict__ yqb,
                                                     const float* __restrict__ s_q,
                                                     unsigned short* __restrict__ ET,
                                                     unsigned short* __restrict__ s1,
                                                     float* __restrict__ cpM,
                                                     float* __restrict__ cpS) {
    int b = blockIdx.y, blk = blockIdx.x, c0 = blk * 64;
    int w = threadIdx.x >> 6, lane = threadIdx.x & 63;
    int lrow = lane & 15, kg = lane >> 4;
    __shared__ float colm4[4][128];
    __shared__ float cols4[4][128];
    const unsigned short* Ab = xcb + ((size_t)(b * Cn + c0 + w * 16 + lrow)) * En + kg * 8;
    const unsigned short* Bb = yqb + ((size_t)(b * Qn + lrow)) * En + kg * 8;
    f32x4 acc[8] = {};
#pragma unroll
    for (int kc = 0; kc < 7; ++kc) {   // K=200: 6 full chunks + tail (kg==0 only)
        bool valid = (kc < 6) || (kg == 0);
        bf16x8 af = bf16x8{0,0,0,0,0,0,0,0};
        if (valid) af = *(const bf16x8*)(Ab + kc * 32);
        bf16x8 bfr[8];
#pragma unroll
        for (int j = 0; j < 8; ++j) {
            bfr[j] = bf16x8{0,0,0,0,0,0,0,0};
            if (valid) bfr[j] = *(const bf16x8*)(Bb + (size_t)j * 16 * En + kc * 32);
        }
#pragma unroll
        for (int j = 0; j < 8; ++j)
            acc[j] = __builtin_amdgcn_mfma_f32_16x16x32_bf16(af, bfr[j], acc[j], 0, 0, 0);
    }
#pragma unroll
    for (int j = 0; j < 8; ++j) {
        float sq = s_q[b * Qn + j * 16 + lrow];
#pragma unroll
        for (int r = 0; r < 4; ++r) acc[j][r] += sq;
    }
    // ---- column (axis c) partial stats over this block's 64 rows ----------
    float lm[8], ls[8];
#pragma unroll
    for (int j = 0; j < 8; ++j) {
        float m = fmaxf(fmaxf(acc[j][0], acc[j][1]), fmaxf(acc[j][2], acc[j][3]));
        m = fmaxf(m, __shfl_xor(m, 16, 64));
        m = fmaxf(m, __shfl_xor(m, 32, 64));
        lm[j] = m;
        float s = __expf(acc[j][0] - m) + __expf(acc[j][1] - m)
                + __expf(acc[j][2] - m) + __expf(acc[j][3] - m);
        s += __shfl_xor(s, 16, 64);
        s += __shfl_xor(s, 32, 64);
        ls[j] = s;
    }
    if (kg == 0) {
#pragma unroll
        for (int j = 0; j < 8; ++j) {
            colm4[w][j * 16 + lrow] = lm[j];
            cols4[w][j * 16 + lrow] = ls[j];
        }
    }
    __syncthreads();
    float mb[8];
#pragma unroll
    for (int j = 0; j < 8; ++j) {
        int q = j * 16 + lrow;
        float m = fmaxf(fmaxf(colm4[0][q], colm4[1][q]), fmaxf(colm4[2][q], colm4[3][q]));
        mb[j] = m;
        if (w == 0 && kg == 0) {
            float sb = cols4[0][q] * __expf(colm4[0][q] - m)
                     + cols4[1][q] * __expf(colm4[1][q] - m)
                     + cols4[2][q] * __expf(colm4[2][q] - m)
                     + cols4[3][q] * __expf(colm4[3][q] - m);
            cpM[(b * 32 + blk) * 128 + q] = m;
            cpS[(b * 32 + blk) * 128 + q] = sb;
        }
    }
    // ---- ET write (transposed): ET[b][q][c0 + w*16 + kg*4 + r] ------------
#pragma unroll
    for (int j = 0; j < 8; ++j) {
        int q = j * 16 + lrow;
        ushort4 o;
        o.x = f2bf(__expf(acc[j][0] - mb[j]));
        o.y = f2bf(__expf(acc[j][1] - mb[j]));
        o.z = f2bf(__expf(acc[j][2] - mb[j]));
        o.w = f2bf(__expf(acc[j][3] - mb[j]));
        *(ushort4*)(ET + ((size_t)(b * Qn + q)) * Cn + c0 + w * 16 + kg * 4) = o;
    }
    // ---- row softmax -> s1 -------------------------------------------------
    size_t rowbase = (size_t)(b * Cn + c0 + w * 16 + kg * 4);
#pragma unroll
    for (int r = 0; r < 4; ++r) {
        float m = acc[0][r];
#pragma unroll
        for (int j = 1; j < 8; ++j) m = fmaxf(m, acc[j][r]);
        for (int d = 1; d < 16; d <<= 1) m = fmaxf(m, __shfl_xor(m, d, 64));
        float ssum = 0.f;
        float e[8];
#pragma unroll
        for (int j = 0; j < 8; ++j) {
            e[j] = __expf(acc[j][r] - m);
            ssum += e[j];
        }
        for (int d = 1; d < 16; d <<= 1) ssum += __shfl_xor(ssum, d, 64);
        float si = 1.f / ssum;
#pragma unroll
        for (int j = 0; j < 8; ++j)
            s1[(rowbase + r) * Qn + j * 16 + lrow] = f2bf(e[j] * si);
    }
}

// ---- k_colcomb: combine 32 block partials -> colM, colSi ------------------
__global__ void k_colcomb(const float* __restrict__ cpM, const float* __restrict__ cpS,
                          float* __restrict__ colM, float* __restrict__ colSi) {
    int b = blockIdx.x, q = threadIdx.x;
    float m = -1e30f;
    for (int k = 0; k < 32; k++) m = fmaxf(m, cpM[(b * 32 + k) * 128 + q]);
    float s = 0.f;
    for (int k = 0; k < 32; k++) s += cpS[(b * 32 + k) * 128 + q] * __expf(cpM[(b * 32 + k) * 128 + q] - m);
    colM[b * 128 + q] = m;
    colSi[b * 128 + q] = 1.f / s;
}

// ---- k_s2corr: in-place ET[b][q][c] *= exp(cpM[b][c/64][q]-colM)*colSi ----
__global__ void k_s2corr(unsigned short* __restrict__ ET, const float* __restrict__ cpM,
                         const float* __restrict__ colM, const float* __restrict__ colSi) {
    int gid = blockIdx.x * 256 + threadIdx.x;   // one per 8 elems: 524288 total
    int row = gid >> 8;                          // b*128 + q
    int b = row >> 7, q = row & 127;
    int cc = (gid & 255) << 3;
    float corr = __expf(cpM[(b * 32 + (cc >> 6)) * 128 + q] - colM[row]) * colSi[row];
    unsigned short* p = ET + (size_t)row * Cn + cc;
    ushort4 v0 = *(ushort4*)p, v1 = *(ushort4*)(p + 4);
    ushort4 o0, o1;
    o0.x = f2bf(bf2f(v0.x) * corr); o0.y = f2bf(bf2f(v0.y) * corr);
    o0.z = f2bf(bf2f(v0.z) * corr); o0.w = f2bf(bf2f(v0.w) * corr);
    o1.x = f2bf(bf2f(v1.x) * corr); o1.y = f2bf(bf2f(v1.y) * corr);
    o1.z = f2bf(bf2f(v1.z) * corr); o1.w = f2bf(bf2f(v1.w) * corr);
    *(ushort4*)p = o0; *(ushort4*)(p + 4) = o1;
}

// ---- k_xqT: xqaT rows [0,200) = xq^T bf16 ---------------------------------
__global__ __launch_bounds__(256) void k_xqT(const float* __restrict__ xq,
                                             unsigned short* __restrict__ xqaT) {
    int et = blockIdx.x, qt = blockIdx.y, b = blockIdx.z;
    int e0 = et * 64, q0 = qt * 64;
    int tid = threadIdx.x;
    __shared__ float t[64][65];
    for (int i = tid; i < 64 * 64; i += 256) {
        int qi = i >> 6, ei = i & 63;
        int e = e0 + ei;
        t[qi][ei] = (e < En) ? xq[((size_t)(b * Qn + q0 + qi)) * En + e] : 0.f;
    }
    __syncthreads();
    for (int i = tid; i < 64 * 64; i += 256) {
        int ei = i >> 6, qi = i & 63;
        int e = e0 + ei;
        if (e < En)
            xqaT[((size_t)(b * 400 + e)) * Qn + q0 + qi] = f2bf(t[qi][ei]);
    }
}

// ---- k_a_part: K-split partials of a^T = xcT @ s2T^T ----------------------
__global__ __launch_bounds__(256) void k_a_part(const unsigned short* __restrict__ s2T,
                                                const unsigned short* __restrict__ xcT,
                                                float* __restrict__ aP) {
    int mt = blockIdx.x, ks = blockIdx.y, b = blockIdx.z;
    int w = threadIdx.x >> 6, lane = threadIdx.x & 63;
    int lrow = lane & 15, kg = lane >> 4;
    const unsigned short* Ab = xcT + ((size_t)(b * EP + mt * 16 + lrow)) * Cn + ks * 512 + kg * 8;
    const unsigned short* B0 = s2T + ((size_t)(b * Qn + w * 16 + lrow)) * Cn + ks * 512 + kg * 8;
    const unsigned short* B1 = B0 + (size_t)64 * Cn;
    f32x4 acc0 = {}, acc1 = {};
#pragma unroll
    for (int kb = 0; kb < 4; ++kb) {
        bf16x8 af[4], bv0[4], bv1[4];
#pragma unroll
        for (int k4 = 0; k4 < 4; ++k4) {
            af[k4]  = *(const bf16x8*)(Ab + (kb * 4 + k4) * 32);
            bv0[k4] = *(const bf16x8*)(B0 + (kb * 4 + k4) * 32);
            bv1[k4] = *(const bf16x8*)(B1 + (kb * 4 + k4) * 32);
        }
#pragma unroll
        for (int k4 = 0; k4 < 4; ++k4) {
            acc0 = __builtin_amdgcn_mfma_f32_16x16x32_bf16(af[k4], bv0[k4], acc0, 0, 0, 0);
            acc1 = __builtin_amdgcn_mfma_f32_16x16x32_bf16(af[k4], bv1[k4], acc1, 0, 0, 0);
        }
    }
    size_t ebase = (size_t)(b * 4 + ks) * EP + mt * 16 + kg * 4;
#pragma unroll
    for (int r = 0; r < 4; ++r) {
        aP[(ebase + r) * Qn + w * 16 + lrow] = acc0[r];
        aP[(ebase + r) * Qn + 64 + w * 16 + lrow] = acc1[r];
    }
}

// ---- k_acomb2: sum 4 partials -> xqaT rows [200,400) ----------------------
__global__ void k_acomb2(const float* __restrict__ aP, unsigned short* __restrict__ xqaT) {
    int gid = blockIdx.x * 256 + threadIdx.x;
    if (gid >= Bn * En * Qn) return;
    int b = gid / (En * Qn), r = gid % (En * Qn);
    int e = r / Qn, q = r % Qn;
    float s = 0.f;
#pragma unroll
    for (int k = 0; k < 4; k++)
        s += aP[((size_t)(b * 4 + k) * EP + e) * Qn + q];
    xqaT[((size_t)(b * 400 + 200 + e)) * Qn + q] = f2bf(s);
}

// ---- phase-1 helper: compile-time NJ/J0; batched loads; pure LDS writes ---
template<int NJ, int J0>
__device__ __forceinline__ void cq_phase(const unsigned short* __restrict__ s1row,
                                         const unsigned short* __restrict__ Bb,
                                         unsigned short* __restrict__ feats,
                                         int rw, int kg, int lrow) {
    bf16x8 a[4];
#pragma unroll
    for (int kc = 0; kc < 4; ++kc) a[kc] = *(const bf16x8*)(s1row + kc * 32);
    f32x4 acc[NJ];
#pragma unroll
    for (int j = 0; j < NJ; ++j) acc[j] = f32x4{0.f, 0.f, 0.f, 0.f};
#pragma unroll
    for (int kc = 0; kc < 4; ++kc) {
        bf16x8 bfr[NJ];
#pragma unroll
        for (int j = 0; j < NJ; ++j)
            bfr[j] = *(const bf16x8*)(Bb + (size_t)(J0 + j) * 16 * Qn + kc * 32);
#pragma unroll
        for (int j = 0; j < NJ; ++j)
            acc[j] = __builtin_amdgcn_mfma_f32_16x16x32_bf16(a[kc], bfr[j], acc[j], 0, 0, 0);
    }
    // pure scatter writes: col<200 -> c2q @ col+200 ; col>=200 -> q2c temp @ col+400
#pragma unroll
    for (int j = 0; j < NJ; ++j) {
        int col = (J0 + j) * 16 + lrow;
        int off = col + (col < 200 ? 200 : 400);
#pragma unroll
        for (int r = 0; r < 4; ++r) {
            int row = rw + kg * 4 + r;
            feats[row * 808 + off] = f2bf(acc[j][r]);
        }
    }
}

// ---- k_tail: fused [c2q|q2c] GEMM + feats + projection, 32-row tiles ------
// grid (64 ctiles, 16 b), 512 threads (8 waves), LDS 60.4 KB -> 2 blocks/CU
__global__ __launch_bounds__(512, 4) void k_tail(const unsigned short* __restrict__ s1,
                                                 const unsigned short* __restrict__ xqaT,
                                                 const float* __restrict__ xc,
                                                 const unsigned short* __restrict__ wpb,
                                                 const float* __restrict__ bp,
                                                 float* __restrict__ out) {
    int b = blockIdx.y, c0 = blockIdx.x * 32;
    int tid = threadIdx.x;
    int w = tid >> 6, lane = tid & 63;
    int lrow = lane & 15, kg = lane >> 4;
    __shared__ unsigned short s1t[32 * 136];   // pad 128->136: 2-way bank (free)
    __shared__ unsigned short feats[32 * 808]; // [c][f], pad 800->808

    // stage S1 tile [32][128] and feats slot-0 (= bf16(xc tile))
    for (int i = tid; i < 32 * 16; i += 512) {
        int row = i >> 4, c8 = i & 15;
        *(bf16x8*)(s1t + row * 136 + c8 * 8) =
            *(const bf16x8*)(s1 + ((size_t)(b * Cn + c0 + row)) * Qn + c8 * 8);
    }
    for (int i = tid; i < 32 * 50; i += 512) {
        int row = i / 50, e4 = (i % 50) * 4;
        float4 v = *(const float4*)(xc + ((size_t)(b * Cn + c0 + row)) * En + e4);
        ushort4 o;
        o.x = f2bf(v.x); o.y = f2bf(v.y); o.z = f2bf(v.z); o.w = f2bf(v.w);
        *(ushort4*)(feats + row * 808 + e4) = o;
    }
    __syncthreads();

    // phase 1: wave w: rows (w&1)*16, col-quarter (w>>1)
    {
        int rw = (w & 1) * 16;
        const unsigned short* s1row = s1t + (rw + lrow) * 136 + kg * 8;
        const unsigned short* Bb = xqaT + ((size_t)b * 400 + lrow) * Qn + kg * 8;
        int quarter = w >> 1;
        if (quarter == 0)      cq_phase<7, 0>(s1row, Bb, feats, rw, kg, lrow);
        else if (quarter == 1) cq_phase<6, 7>(s1row, Bb, feats, rw, kg, lrow);
        else if (quarter == 2) cq_phase<6, 13>(s1row, Bb, feats, rw, kg, lrow);
        else                   cq_phase<6, 19>(s1row, Bb, feats, rw, kg, lrow);
    }
    __syncthreads();

    // mid-pass: slot2 = x*c2q, slot3 = x*q2c (vectorized, aligned bf16x8)
    for (int i = tid; i < 32 * 25; i += 512) {
        int row = i / 25, e8 = (i % 25) * 8;
        unsigned short* fr = feats + row * 808;
        bf16x8 x  = *(bf16x8*)(fr + e8);
        bf16x8 c2 = *(bf16x8*)(fr + 200 + e8);
        bf16x8 q2 = *(bf16x8*)(fr + 600 + e8);
        *(bf16x8*)(fr + 400 + e8) = mul8(x, c2);
        *(bf16x8*)(fr + 600 + e8) = mul8(x, q2);
    }
    __syncthreads();

    // phase 2: out[32][128] = feats @ wp^T. wave w: cols w*16..+16, rows m*16.
    {
        f32x4 acc[2] = {};
        const unsigned short* Bb = wpb + ((size_t)(w * 16 + lrow)) * Fn + kg * 8;
#pragma unroll
        for (int kb = 0; kb < 5; ++kb) {
            bf16x8 bfr[5];
#pragma unroll
            for (int k5 = 0; k5 < 5; ++k5)
                bfr[k5] = *(const bf16x8*)(Bb + (kb * 5 + k5) * 32);
#pragma unroll
            for (int k5 = 0; k5 < 5; ++k5) {
#pragma unroll
                for (int m = 0; m < 2; ++m) {
                    bf16x8 af = *(const bf16x8*)(feats + (m * 16 + lrow) * 808 + kg * 8 + (kb * 5 + k5) * 32);
                    acc[m] = __builtin_amdgcn_mfma_f32_16x16x32_bf16(af, bfr[k5], acc[m], 0, 0, 0);
                }
            }
        }
        int o = w * 16 + lrow;
        float bpv = bp[o];
#pragma unroll
        for (int m = 0; m < 2; ++m)
#pragma unroll
            for (int r = 0; r < 4; ++r)
                out[((size_t)(b * Cn + c0 + m * 16 + kg * 4 + r)) * On + o] = acc[m][r] + bpv;
    }
}

extern "C" void kernel_launch(void* const* d_in, const int* in_sizes, int n_in,
                              void* d_out, int out_size, void* d_ws, size_t ws_size,
                              hipStream_t stream) {
    const float* xc = (const float*)d_in[0];
    const float* xq = (const float*)d_in[1];
    const float* wsim = (const float*)d_in[2];
    const float* wp = (const float*)d_in[3];
    const float* bp = (const float*)d_in[4];
    float* out = (float*)d_out;
    float* ws = (float*)d_ws;

    unsigned short* ET_s2T = (unsigned short*)ws;                  // 4,194,304 bf16 (E^T, scaled in place -> s2T)
    unsigned short* s1_bf  = (unsigned short*)(ws + 2097152);      // 4,194,304 bf16
    // xc_bf dead after k_scores_mfma; aP aliases it
    unsigned short* xc_bf  = (unsigned short*)(ws + 4194304);      // 6,553,600 bf16
    float* aP              = ws + 4194304;                         // 1,703,936 f (alias)
    unsigned short* xcT_bf = (unsigned short*)(ws + 7471104);      // 6,815,744 bf16
    unsigned short* yq_bf  = (unsigned short*)(ws + 10878976);     //   409,600 bf16
    unsigned short* xqaT_bf= (unsigned short*)(ws + 11083776);     //   819,200 bf16
    unsigned short* wp_bf  = (unsigned short*)(ws + 11493376);     //   102,400 bf16
    float* s_q   = ws + 11544576;   //  2,048 f
    float* cpM   = ws + 11546624;   // 65,536 f  [b][32][128]
    float* cpS   = ws + 11612160;   // 65,536 f
    float* colM  = ws + 11677696;   //  2,048 f
    float* colSi = ws + 11679744;   //  2,048 f
    // total: 11,681,792 floats = 46.7 MB

    k_yq<<<512, 256, 0, stream>>>(xq, wsim, yq_bf, s_q);
    k_prep_wp<<<100, 256, 0, stream>>>(wp, wp_bf);
    k_prep_xc<<<dim3(32, 4, 16), 256, 0, stream>>>(xc, xc_bf, xcT_bf);
    k_scores_mfma<<<dim3(32, 16), 256, 0, stream>>>(xc_bf, yq_bf, s_q, ET_s2T, s1_bf, cpM, cpS);
    k_colcomb<<<16, 128, 0, stream>>>(cpM, cpS, colM, colSi);
    k_s2corr<<<2048, 256, 0, stream>>>(ET_s2T, cpM, colM, colSi);
    k_xqT<<<dim3(4, 2, 16), 256, 0, stream>>>(xq, xqaT_bf);
    // xc_bf dead from here; aP aliases it
    k_a_part<<<dim3(13, 4, 16), 256, 0, stream>>>(ET_s2T, xcT_bf, aP);
    k_acomb2<<<1600, 256, 0, stream>>>(aP, xqaT_bf);
    k_tail<<<dim3(64, 16), 512, 0, stream>>>(s1_bf, xqaT_bf, xc, wp_bf, bp, out);
}

// Round 8
// 109.696 us; speedup vs baseline: 1.7352x; 1.1214x over previous
//
#include <hip/hip_runtime.h>
#include <hip/hip_bf16.h>

#define Bn 16
#define Cn 2048
#define Qn 128
#define En 200
#define Fn 800
#define On 128
#define EP 208  // padded e-rows for xcT

typedef float f32x4 __attribute__((ext_vector_type(4)));
typedef __bf16 bf16x8 __attribute__((ext_vector_type(8)));

__device__ __forceinline__ unsigned short f2bf(float f) {
    union { float f; unsigned u; } v; v.f = f;
    unsigned r = v.u + 0x7FFF + ((v.u >> 16) & 1);
    return (unsigned short)(r >> 16);
}
__device__ __forceinline__ float bf2f(unsigned short h) {
    union { unsigned u; float f; } v; v.u = (unsigned)h << 16;
    return v.f;
}
__device__ __forceinline__ bf16x8 mul8(bf16x8 a, bf16x8 b) {
    bf16x8 o;
#pragma unroll
    for (int k = 0; k < 8; ++k) o[k] = (__bf16)((float)a[k] * (float)b[k]);
    return o;
}

// ---- k_prep_misc: fused {yq+s_q | wp->bf16 | xq^T} by blockIdx range ------
__global__ __launch_bounds__(256) void k_prep_misc(const float* __restrict__ xq,
                                                   const float* __restrict__ wsim,
                                                   const float* __restrict__ wp,
                                                   unsigned short* __restrict__ yqb,
                                                   float* __restrict__ s_q,
                                                   unsigned short* __restrict__ wpb,
                                                   unsigned short* __restrict__ xqaT) {
    int bx = blockIdx.x;
    if (bx < 512) {
        // yq part
        int wid = (bx * 256 + threadIdx.x) >> 6;
        int lane = threadIdx.x & 63;
        const float* xrow = xq + (size_t)wid * En;
        float s = 0.f;
        for (int e = lane; e < En; e += 64) {
            float x = xrow[e];
            yqb[(size_t)wid * En + e] = f2bf(x * wsim[400 + e] + wsim[e]);
            s += x * wsim[200 + e];
        }
        for (int i = 32; i; i >>= 1) s += __shfl_xor(s, i, 64);
        if (lane == 0) s_q[wid] = s;
    } else if (bx < 612) {
        // wp cast part
        int gid = (bx - 512) * 256 + threadIdx.x;
        int base = gid * 4;
        if (base < On * Fn) {
            float4 v = *(const float4*)(wp + base);
            ushort4 o;
            o.x = f2bf(v.x); o.y = f2bf(v.y); o.z = f2bf(v.z); o.w = f2bf(v.w);
            *(ushort4*)(wpb + base) = o;
        }
    } else {
        // xqT part: xqaT rows [0,200) = xq^T
        int lb = bx - 612;                 // 128 blocks: (4 et, 2 qt, 16 b)
        int et = lb & 3, qt = (lb >> 2) & 1, b = lb >> 3;
        int e0 = et * 64, q0 = qt * 64;
        int tid = threadIdx.x;
        __shared__ float t[64][65];
        for (int i = tid; i < 64 * 64; i += 256) {
            int qi = i >> 6, ei = i & 63;
            int e = e0 + ei;
            t[qi][ei] = (e < En) ? xq[((size_t)(b * Qn + q0 + qi)) * En + e] : 0.f;
        }
        __syncthreads();
        for (int i = tid; i < 64 * 64; i += 256) {
            int ei = i >> 6, qi = i & 63;
            int e = e0 + ei;
            if (e < En)
                xqaT[((size_t)(b * 400 + e)) * Qn + q0 + qi] = f2bf(t[qi][ei]);
        }
    }
}

// ---- k_prep_xc: one pass over fp32 xc -> xc_bf (row-major) + xcT (trans) --
__global__ __launch_bounds__(256) void k_prep_xc(const float* __restrict__ xc,
                                                 unsigned short* __restrict__ xcb,
                                                 unsigned short* __restrict__ xcT) {
    int ct = blockIdx.x, et = blockIdx.y, b = blockIdx.z;   // 32, 4, 16
    int c0 = ct * 64, e0 = et * 64;
    int tid = threadIdx.x;
    __shared__ float t[64][65];
    for (int i = tid; i < 64 * 64; i += 256) {
        int ci = i >> 6, ei = i & 63;
        int e = e0 + ei;
        t[ci][ei] = (e < En) ? xc[((size_t)(b * Cn + c0 + ci)) * En + e] : 0.f;
    }
    __syncthreads();
    for (int i = tid; i < 64 * 16; i += 256) {
        int ci = i >> 4, g4 = (i & 15) * 4;
        int e = e0 + g4;
        if (e + 3 < En) {
            ushort4 o;
            o.x = f2bf(t[ci][g4]); o.y = f2bf(t[ci][g4 + 1]);
            o.z = f2bf(t[ci][g4 + 2]); o.w = f2bf(t[ci][g4 + 3]);
            *(ushort4*)(xcb + ((size_t)(b * Cn + c0 + ci)) * En + e) = o;
        }
    }
    for (int i = tid; i < 64 * 64; i += 256) {
        int ei = i >> 6, ci = i & 63;
        int e = e0 + ei;
        if (e < EP)
            xcT[((size_t)(b * EP + e)) * Cn + c0 + ci] = f2bf(t[ci][ei]);
    }
}

// ---- k_scores_mfma: scores GEMM + fused row softmax (s1) + block-local ----
__global__ __launch_bounds__(256) void k_scores_mfma(const unsigned short* __restrict__ xcb,
                                                     const unsigned short* __restrict__ yqb,
                                                     const float* __restrict__ s_q,
                                                     unsigned short* __restrict__ ET,
                                                     unsigned short* __restrict__ s1,
                                                     float* __restrict__ cpM,
                                                     float* __restrict__ cpS) {
    int b = blockIdx.y, blk = blockIdx.x, c0 = blk * 64;
    int w = threadIdx.x >> 6, lane = threadIdx.x & 63;
    int lrow = lane & 15, kg = lane >> 4;
    __shared__ float colm4[4][128];
    __shared__ float cols4[4][128];
    const unsigned short* Ab = xcb + ((size_t)(b * Cn + c0 + w * 16 + lrow)) * En + kg * 8;
    const unsigned short* Bb = yqb + ((size_t)(b * Qn + lrow)) * En + kg * 8;
    f32x4 acc[8] = {};
#pragma unroll
    for (int kc = 0; kc < 7; ++kc) {
        bool valid = (kc < 6) || (kg == 0);
        bf16x8 af = bf16x8{0,0,0,0,0,0,0,0};
        if (valid) af = *(const bf16x8*)(Ab + kc * 32);
        bf16x8 bfr[8];
#pragma unroll
        for (int j = 0; j < 8; ++j) {
            bfr[j] = bf16x8{0,0,0,0,0,0,0,0};
            if (valid) bfr[j] = *(const bf16x8*)(Bb + (size_t)j * 16 * En + kc * 32);
        }
#pragma unroll
        for (int j = 0; j < 8; ++j)
            acc[j] = __builtin_amdgcn_mfma_f32_16x16x32_bf16(af, bfr[j], acc[j], 0, 0, 0);
    }
#pragma unroll
    for (int j = 0; j < 8; ++j) {
        float sq = s_q[b * Qn + j * 16 + lrow];
#pragma unroll
        for (int r = 0; r < 4; ++r) acc[j][r] += sq;
    }
    float lm[8], ls[8];
#pragma unroll
    for (int j = 0; j < 8; ++j) {
        float m = fmaxf(fmaxf(acc[j][0], acc[j][1]), fmaxf(acc[j][2], acc[j][3]));
        m = fmaxf(m, __shfl_xor(m, 16, 64));
        m = fmaxf(m, __shfl_xor(m, 32, 64));
        lm[j] = m;
        float s = __expf(acc[j][0] - m) + __expf(acc[j][1] - m)
                + __expf(acc[j][2] - m) + __expf(acc[j][3] - m);
        s += __shfl_xor(s, 16, 64);
        s += __shfl_xor(s, 32, 64);
        ls[j] = s;
    }
    if (kg == 0) {
#pragma unroll
        for (int j = 0; j < 8; ++j) {
            colm4[w][j * 16 + lrow] = lm[j];
            cols4[w][j * 16 + lrow] = ls[j];
        }
    }
    __syncthreads();
    float mb[8];
#pragma unroll
    for (int j = 0; j < 8; ++j) {
        int q = j * 16 + lrow;
        float m = fmaxf(fmaxf(colm4[0][q], colm4[1][q]), fmaxf(colm4[2][q], colm4[3][q]));
        mb[j] = m;
        if (w == 0 && kg == 0) {
            float sb = cols4[0][q] * __expf(colm4[0][q] - m)
                     + cols4[1][q] * __expf(colm4[1][q] - m)
                     + cols4[2][q] * __expf(colm4[2][q] - m)
                     + cols4[3][q] * __expf(colm4[3][q] - m);
            cpM[(b * 32 + blk) * 128 + q] = m;
            cpS[(b * 32 + blk) * 128 + q] = sb;
        }
    }
#pragma unroll
    for (int j = 0; j < 8; ++j) {
        int q = j * 16 + lrow;
        ushort4 o;
        o.x = f2bf(__expf(acc[j][0] - mb[j]));
        o.y = f2bf(__expf(acc[j][1] - mb[j]));
        o.z = f2bf(__expf(acc[j][2] - mb[j]));
        o.w = f2bf(__expf(acc[j][3] - mb[j]));
        *(ushort4*)(ET + ((size_t)(b * Qn + q)) * Cn + c0 + w * 16 + kg * 4) = o;
    }
    size_t rowbase = (size_t)(b * Cn + c0 + w * 16 + kg * 4);
#pragma unroll
    for (int r = 0; r < 4; ++r) {
        float m = acc[0][r];
#pragma unroll
        for (int j = 1; j < 8; ++j) m = fmaxf(m, acc[j][r]);
        for (int d = 1; d < 16; d <<= 1) m = fmaxf(m, __shfl_xor(m, d, 64));
        float ssum = 0.f;
        float e[8];
#pragma unroll
        for (int j = 0; j < 8; ++j) {
            e[j] = __expf(acc[j][r] - m);
            ssum += e[j];
        }
        for (int d = 1; d < 16; d <<= 1) ssum += __shfl_xor(ssum, d, 64);
        float si = 1.f / ssum;
#pragma unroll
        for (int j = 0; j < 8; ++j)
            s1[(rowbase + r) * Qn + j * 16 + lrow] = f2bf(e[j] * si);
    }
}

// ---- k_colcomb ------------------------------------------------------------
__global__ void k_colcomb(const float* __restrict__ cpM, const float* __restrict__ cpS,
                          float* __restrict__ colM, float* __restrict__ colSi) {
    int b = blockIdx.x, q = threadIdx.x;
    float m = -1e30f;
    for (int k = 0; k < 32; k++) m = fmaxf(m, cpM[(b * 32 + k) * 128 + q]);
    float s = 0.f;
    for (int k = 0; k < 32; k++) s += cpS[(b * 32 + k) * 128 + q] * __expf(cpM[(b * 32 + k) * 128 + q] - m);
    colM[b * 128 + q] = m;
    colSi[b * 128 + q] = 1.f / s;
}

// ---- k_s2corr: in-place ET *= exp(cpM-colM)*colSi -------------------------
__global__ void k_s2corr(unsigned short* __restrict__ ET, const float* __restrict__ cpM,
                         const float* __restrict__ colM, const float* __restrict__ colSi) {
    int gid = blockIdx.x * 256 + threadIdx.x;
    int row = gid >> 8;
    int b = row >> 7, q = row & 127;
    int cc = (gid & 255) << 3;
    float corr = __expf(cpM[(b * 32 + (cc >> 6)) * 128 + q] - colM[row]) * colSi[row];
    unsigned short* p = ET + (size_t)row * Cn + cc;
    ushort4 v0 = *(ushort4*)p, v1 = *(ushort4*)(p + 4);
    ushort4 o0, o1;
    o0.x = f2bf(bf2f(v0.x) * corr); o0.y = f2bf(bf2f(v0.y) * corr);
    o0.z = f2bf(bf2f(v0.z) * corr); o0.w = f2bf(bf2f(v0.w) * corr);
    o1.x = f2bf(bf2f(v1.x) * corr); o1.y = f2bf(bf2f(v1.y) * corr);
    o1.z = f2bf(bf2f(v1.z) * corr); o1.w = f2bf(bf2f(v1.w) * corr);
    *(ushort4*)p = o0; *(ushort4*)(p + 4) = o1;
}

// ---- k_a_part: K-split partials of a^T = xcT @ s2T^T ----------------------
__global__ __launch_bounds__(256) void k_a_part(const unsigned short* __restrict__ s2T,
                                                const unsigned short* __restrict__ xcT,
                                                float* __restrict__ aP) {
    int mt = blockIdx.x, ks = blockIdx.y, b = blockIdx.z;
    int w = threadIdx.x >> 6, lane = threadIdx.x & 63;
    int lrow = lane & 15, kg = lane >> 4;
    const unsigned short* Ab = xcT + ((size_t)(b * EP + mt * 16 + lrow)) * Cn + ks * 512 + kg * 8;
    const unsigned short* B0 = s2T + ((size_t)(b * Qn + w * 16 + lrow)) * Cn + ks * 512 + kg * 8;
    const unsigned short* B1 = B0 + (size_t)64 * Cn;
    f32x4 acc0 = {}, acc1 = {};
#pragma unroll
    for (int kb = 0; kb < 4; ++kb) {
        bf16x8 af[4], bv0[4], bv1[4];
#pragma unroll
        for (int k4 = 0; k4 < 4; ++k4) {
            af[k4]  = *(const bf16x8*)(Ab + (kb * 4 + k4) * 32);
            bv0[k4] = *(const bf16x8*)(B0 + (kb * 4 + k4) * 32);
            bv1[k4] = *(const bf16x8*)(B1 + (kb * 4 + k4) * 32);
        }
#pragma unroll
        for (int k4 = 0; k4 < 4; ++k4) {
            acc0 = __builtin_amdgcn_mfma_f32_16x16x32_bf16(af[k4], bv0[k4], acc0, 0, 0, 0);
            acc1 = __builtin_amdgcn_mfma_f32_16x16x32_bf16(af[k4], bv1[k4], acc1, 0, 0, 0);
        }
    }
    size_t ebase = (size_t)(b * 4 + ks) * EP + mt * 16 + kg * 4;
#pragma unroll
    for (int r = 0; r < 4; ++r) {
        aP[(ebase + r) * Qn + w * 16 + lrow] = acc0[r];
        aP[(ebase + r) * Qn + 64 + w * 16 + lrow] = acc1[r];
    }
}

// ---- k_acomb2: sum 4 partials -> xqaT rows [200,400) ----------------------
__global__ void k_acomb2(const float* __restrict__ aP, unsigned short* __restrict__ xqaT) {
    int gid = blockIdx.x * 256 + threadIdx.x;
    if (gid >= Bn * En * Qn) return;
    int b = gid / (En * Qn), r = gid % (En * Qn);
    int e = r / Qn, q = r % Qn;
    float s = 0.f;
#pragma unroll
    for (int k = 0; k < 4; k++)
        s += aP[((size_t)(b * 4 + k) * EP + e) * Qn + q];
    xqaT[((size_t)(b * 400 + 200 + e)) * Qn + q] = f2bf(s);
}

// ---- phase-1 helper: wave owns NJ n-tiles (J0..J0+NJ), ALL 4 m-tiles ------
// B-frag reuse = 4 (vs 1 before). acc indices compile-time.
template<int NJ>
__device__ __forceinline__ void cq_phase64(const unsigned short* __restrict__ s1t,
                                           const unsigned short* __restrict__ xqaT_b,
                                           unsigned short* __restrict__ feats,
                                           int J0, int kg, int lrow) {
    f32x4 acc[NJ][4];
#pragma unroll
    for (int j = 0; j < NJ; ++j)
#pragma unroll
        for (int m = 0; m < 4; ++m) acc[j][m] = f32x4{0.f, 0.f, 0.f, 0.f};
#pragma unroll
    for (int kc = 0; kc < 4; ++kc) {
        bf16x8 a[4];
#pragma unroll
        for (int m = 0; m < 4; ++m)
            a[m] = *(const bf16x8*)(s1t + (m * 16 + lrow) * 136 + kg * 8 + kc * 32);
        bf16x8 bv[NJ];
#pragma unroll
        for (int j = 0; j < NJ; ++j)
            bv[j] = *(const bf16x8*)(xqaT_b + ((size_t)((J0 + j) * 16 + lrow)) * Qn + kg * 8 + kc * 32);
#pragma unroll
        for (int j = 0; j < NJ; ++j)
#pragma unroll
            for (int m = 0; m < 4; ++m)
                acc[j][m] = __builtin_amdgcn_mfma_f32_16x16x32_bf16(a[m], bv[j], acc[j][m], 0, 0, 0);
    }
#pragma unroll
    for (int j = 0; j < NJ; ++j) {
        int col = (J0 + j) * 16 + lrow;
        int off = col + (col < 200 ? 200 : 400);
#pragma unroll
        for (int m = 0; m < 4; ++m)
#pragma unroll
            for (int r = 0; r < 4; ++r)
                feats[(m * 16 + kg * 4 + r) * 808 + off] = f2bf(acc[j][m][r]);
    }
}

// ---- k_tail: fused [c2q|q2c] + feats + projection, 64-row tiles -----------
// grid (32 ctiles, 16 b), 512 threads (8 waves), LDS 120.8 KB, 1 block/CU
__global__ __launch_bounds__(512, 2) void k_tail(const unsigned short* __restrict__ s1,
                                                 const unsigned short* __restrict__ xqaT,
                                                 const float* __restrict__ xc,
                                                 const unsigned short* __restrict__ wpb,
                                                 const float* __restrict__ bp,
                                                 float* __restrict__ out) {
    int b = blockIdx.y, c0 = blockIdx.x * 64;
    int tid = threadIdx.x;
    int w = tid >> 6, lane = tid & 63;
    int lrow = lane & 15, kg = lane >> 4;
    __shared__ unsigned short s1t[64 * 136];
    __shared__ unsigned short feats[64 * 808];

    for (int i = tid; i < 64 * 16; i += 512) {
        int row = i >> 4, c8 = i & 15;
        *(bf16x8*)(s1t + row * 136 + c8 * 8) =
            *(const bf16x8*)(s1 + ((size_t)(b * Cn + c0 + row)) * Qn + c8 * 8);
    }
    for (int i = tid; i < 64 * 50; i += 512) {
        int row = i / 50, e4 = (i % 50) * 4;
        float4 v = *(const float4*)(xc + ((size_t)(b * Cn + c0 + row)) * En + e4);
        ushort4 o;
        o.x = f2bf(v.x); o.y = f2bf(v.y); o.z = f2bf(v.z); o.w = f2bf(v.w);
        *(ushort4*)(feats + row * 808 + e4) = o;
    }
    __syncthreads();

    // phase 1: wave w owns n-tiles [3w, 3w+3) (wave 7: [21,25)), all 64 rows
    {
        const unsigned short* xqaT_b = xqaT + (size_t)b * 400 * Qn;
        if (w < 7) cq_phase64<3>(s1t, xqaT_b, feats, w * 3, kg, lrow);
        else       cq_phase64<4>(s1t, xqaT_b, feats, 21, kg, lrow);
    }
    __syncthreads();

    // mid-pass: slot2 = x*c2q, slot3 = x*q2c
    for (int i = tid; i < 64 * 25; i += 512) {
        int row = i / 25, e8 = (i % 25) * 8;
        unsigned short* fr = feats + row * 808;
        bf16x8 x  = *(bf16x8*)(fr + e8);
        bf16x8 c2 = *(bf16x8*)(fr + 200 + e8);
        bf16x8 q2 = *(bf16x8*)(fr + 600 + e8);
        *(bf16x8*)(fr + 400 + e8) = mul8(x, c2);
        *(bf16x8*)(fr + 600 + e8) = mul8(x, q2);
    }
    __syncthreads();

    // phase 2: wave w: n-pair p=w>>1 (cols 32p..32p+32), row-half h=w&1
    // per kc: 2 B-loads + 2 A ds_reads -> 4 MFMAs
    {
        int p = w >> 1, h = w & 1;
        f32x4 acc[2][2];
#pragma unroll
        for (int n = 0; n < 2; ++n)
#pragma unroll
            for (int m = 0; m < 2; ++m) acc[n][m] = f32x4{0.f, 0.f, 0.f, 0.f};
        const unsigned short* B0 = wpb + ((size_t)(p * 32 + lrow)) * Fn + kg * 8;
        const unsigned short* A0 = feats + (h * 32 + lrow) * 808 + kg * 8;
#pragma unroll 5
        for (int kc = 0; kc < 25; ++kc) {
            bf16x8 b0 = *(const bf16x8*)(B0 + kc * 32);
            bf16x8 b1 = *(const bf16x8*)(B0 + (size_t)16 * Fn + kc * 32);
            bf16x8 a0 = *(const bf16x8*)(A0 + kc * 32);
            bf16x8 a1 = *(const bf16x8*)(A0 + 16 * 808 + kc * 32);
            acc[0][0] = __builtin_amdgcn_mfma_f32_16x16x32_bf16(a0, b0, acc[0][0], 0, 0, 0);
            acc[0][1] = __builtin_amdgcn_mfma_f32_16x16x32_bf16(a1, b0, acc[0][1], 0, 0, 0);
            acc[1][0] = __builtin_amdgcn_mfma_f32_16x16x32_bf16(a0, b1, acc[1][0], 0, 0, 0);
            acc[1][1] = __builtin_amdgcn_mfma_f32_16x16x32_bf16(a1, b1, acc[1][1], 0, 0, 0);
        }
#pragma unroll
        for (int n = 0; n < 2; ++n) {
            int o = p * 32 + n * 16 + lrow;
            float bpv = bp[o];
#pragma unroll
            for (int m = 0; m < 2; ++m)
#pragma unroll
                for (int r = 0; r < 4; ++r)
                    out[((size_t)(b * Cn + c0 + h * 32 + m * 16 + kg * 4 + r)) * On + o] = acc[n][m][r] + bpv;
        }
    }
}

extern "C" void kernel_launch(void* const* d_in, const int* in_sizes, int n_in,
                              void* d_out, int out_size, void* d_ws, size_t ws_size,
                              hipStream_t stream) {
    const float* xc = (const float*)d_in[0];
    const float* xq = (const float*)d_in[1];
    const float* wsim = (const float*)d_in[2];
    const float* wp = (const float*)d_in[3];
    const float* bp = (const float*)d_in[4];
    float* out = (float*)d_out;
    float* ws = (float*)d_ws;

    unsigned short* ET_s2T = (unsigned short*)ws;                  // 4,194,304 bf16
    unsigned short* s1_bf  = (unsigned short*)(ws + 2097152);      // 4,194,304 bf16
    unsigned short* xc_bf  = (unsigned short*)(ws + 4194304);      // 6,553,600 bf16
    float* aP              = ws + 4194304;                         // alias (xc_bf dead)
    unsigned short* xcT_bf = (unsigned short*)(ws + 7471104);      // 6,815,744 bf16
    unsigned short* yq_bf  = (unsigned short*)(ws + 10878976);     //   409,600 bf16
    unsigned short* xqaT_bf= (unsigned short*)(ws + 11083776);     //   819,200 bf16
    unsigned short* wp_bf  = (unsigned short*)(ws + 11493376);     //   102,400 bf16
    float* s_q   = ws + 11544576;
    float* cpM   = ws + 11546624;
    float* cpS   = ws + 11612160;
    float* colM  = ws + 11677696;
    float* colSi = ws + 11679744;

    k_prep_misc<<<740, 256, 0, stream>>>(xq, wsim, wp, yq_bf, s_q, wp_bf, xqaT_bf);
    k_prep_xc<<<dim3(32, 4, 16), 256, 0, stream>>>(xc, xc_bf, xcT_bf);
    k_scores_mfma<<<dim3(32, 16), 256, 0, stream>>>(xc_bf, yq_bf, s_q, ET_s2T, s1_bf, cpM, cpS);
    k_colcomb<<<16, 128, 0, stream>>>(cpM, cpS, colM, colSi);
    k_s2corr<<<2048, 256, 0, stream>>>(ET_s2T, cpM, colM, colSi);
    k_a_part<<<dim3(13, 4, 16), 256, 0, stream>>>(ET_s2T, xcT_bf, aP);
    k_acomb2<<<1600, 256, 0, stream>>>(aP, xqaT_bf);
    k_tail<<<dim3(32, 16), 512, 0, stream>>>(s1_bf, xqaT_bf, xc, wp_bf, bp, out);
}

// Round 9
// 95.799 us; speedup vs baseline: 1.9869x; 1.1451x over previous
//
#include <hip/hip_runtime.h>
#include <hip/hip_bf16.h>

#define Bn 16
#define Cn 2048
#define Qn 128
#define En 200
#define Fn 800
#define On 128
#define EP 208  // padded e-rows for xcT

typedef float f32x4 __attribute__((ext_vector_type(4)));
typedef __bf16 bf16x8 __attribute__((ext_vector_type(8)));

__device__ __forceinline__ unsigned short f2bf(float f) {
    union { float f; unsigned u; } v; v.f = f;
    unsigned r = v.u + 0x7FFF + ((v.u >> 16) & 1);
    return (unsigned short)(r >> 16);
}
__device__ __forceinline__ float bf2f(unsigned short h) {
    union { unsigned u; float f; } v; v.u = (unsigned)h << 16;
    return v.f;
}
__device__ __forceinline__ bf16x8 mul8(bf16x8 a, bf16x8 b) {
    bf16x8 o;
#pragma unroll
    for (int k = 0; k < 8; ++k) o[k] = (__bf16)((float)a[k] * (float)b[k]);
    return o;
}
__device__ __forceinline__ bf16x8 scale8(bf16x8 a, float s) {
    bf16x8 o;
#pragma unroll
    for (int k = 0; k < 8; ++k) o[k] = (__bf16)((float)a[k] * s);
    return o;
}

// ---- k_prep_all: {yq+s_q | wp->bf16 | xq^T | xc->bf16+xc^T} ---------------
__global__ __launch_bounds__(256) void k_prep_all(const float* __restrict__ xq,
                                                  const float* __restrict__ wsim,
                                                  const float* __restrict__ wp,
                                                  const float* __restrict__ xc,
                                                  unsigned short* __restrict__ yqb,
                                                  float* __restrict__ s_q,
                                                  unsigned short* __restrict__ wpb,
                                                  unsigned short* __restrict__ xqaT,
                                                  unsigned short* __restrict__ xcb,
                                                  unsigned short* __restrict__ xcT) {
    int bx = blockIdx.x;
    if (bx < 512) {
        int wid = (bx * 256 + threadIdx.x) >> 6;
        int lane = threadIdx.x & 63;
        const float* xrow = xq + (size_t)wid * En;
        float s = 0.f;
        for (int e = lane; e < En; e += 64) {
            float x = xrow[e];
            yqb[(size_t)wid * En + e] = f2bf(x * wsim[400 + e] + wsim[e]);
            s += x * wsim[200 + e];
        }
        for (int i = 32; i; i >>= 1) s += __shfl_xor(s, i, 64);
        if (lane == 0) s_q[wid] = s;
    } else if (bx < 612) {
        int gid = (bx - 512) * 256 + threadIdx.x;
        int base = gid * 4;
        if (base < On * Fn) {
            float4 v = *(const float4*)(wp + base);
            ushort4 o;
            o.x = f2bf(v.x); o.y = f2bf(v.y); o.z = f2bf(v.z); o.w = f2bf(v.w);
            *(ushort4*)(wpb + base) = o;
        }
    } else if (bx < 740) {
        int lb = bx - 612;                 // 128 blocks: (4 et, 2 qt, 16 b)
        int et = lb & 3, qt = (lb >> 2) & 1, b = lb >> 3;
        int e0 = et * 64, q0 = qt * 64;
        int tid = threadIdx.x;
        __shared__ float t[64][65];
        for (int i = tid; i < 64 * 64; i += 256) {
            int qi = i >> 6, ei = i & 63;
            int e = e0 + ei;
            t[qi][ei] = (e < En) ? xq[((size_t)(b * Qn + q0 + qi)) * En + e] : 0.f;
        }
        __syncthreads();
        for (int i = tid; i < 64 * 64; i += 256) {
            int ei = i >> 6, qi = i & 63;
            int e = e0 + ei;
            if (e < En)
                xqaT[((size_t)(b * 400 + e)) * Qn + q0 + qi] = f2bf(t[qi][ei]);
        }
    } else {
        int lb = bx - 740;                 // 2048 blocks: (32 ct, 4 et, 16 b)
        int ct = lb & 31, et = (lb >> 5) & 3, b = lb >> 7;
        int c0 = ct * 64, e0 = et * 64;
        int tid = threadIdx.x;
        __shared__ float t[64][65];
        for (int i = tid; i < 64 * 64; i += 256) {
            int ci = i >> 6, ei = i & 63;
            int e = e0 + ei;
            t[ci][ei] = (e < En) ? xc[((size_t)(b * Cn + c0 + ci)) * En + e] : 0.f;
        }
        __syncthreads();
        for (int i = tid; i < 64 * 16; i += 256) {
            int ci = i >> 4, g4 = (i & 15) * 4;
            int e = e0 + g4;
            if (e + 3 < En) {
                ushort4 o;
                o.x = f2bf(t[ci][g4]); o.y = f2bf(t[ci][g4 + 1]);
                o.z = f2bf(t[ci][g4 + 2]); o.w = f2bf(t[ci][g4 + 3]);
                *(ushort4*)(xcb + ((size_t)(b * Cn + c0 + ci)) * En + e) = o;
            }
        }
        for (int i = tid; i < 64 * 64; i += 256) {
            int ei = i >> 6, ci = i & 63;
            int e = e0 + ei;
            if (e < EP)
                xcT[((size_t)(b * EP + e)) * Cn + c0 + ci] = f2bf(t[ci][ei]);
        }
    }
}

// ---- k_scores_mfma: scores GEMM + fused row softmax (s1) + block-local ----
__global__ __launch_bounds__(256) void k_scores_mfma(const unsigned short* __restrict__ xcb,
                                                     const unsigned short* __restrict__ yqb,
                                                     const float* __restrict__ s_q,
                                                     unsigned short* __restrict__ ET,
                                                     unsigned short* __restrict__ s1,
                                                     float* __restrict__ cpM,
                                                     float* __restrict__ cpS) {
    int b = blockIdx.y, blk = blockIdx.x, c0 = blk * 64;
    int w = threadIdx.x >> 6, lane = threadIdx.x & 63;
    int lrow = lane & 15, kg = lane >> 4;
    __shared__ float colm4[4][128];
    __shared__ float cols4[4][128];
    const unsigned short* Ab = xcb + ((size_t)(b * Cn + c0 + w * 16 + lrow)) * En + kg * 8;
    const unsigned short* Bb = yqb + ((size_t)(b * Qn + lrow)) * En + kg * 8;
    f32x4 acc[8] = {};
#pragma unroll
    for (int kc = 0; kc < 7; ++kc) {
        bool valid = (kc < 6) || (kg == 0);
        bf16x8 af = bf16x8{0,0,0,0,0,0,0,0};
        if (valid) af = *(const bf16x8*)(Ab + kc * 32);
        bf16x8 bfr[8];
#pragma unroll
        for (int j = 0; j < 8; ++j) {
            bfr[j] = bf16x8{0,0,0,0,0,0,0,0};
            if (valid) bfr[j] = *(const bf16x8*)(Bb + (size_t)j * 16 * En + kc * 32);
        }
#pragma unroll
        for (int j = 0; j < 8; ++j)
            acc[j] = __builtin_amdgcn_mfma_f32_16x16x32_bf16(af, bfr[j], acc[j], 0, 0, 0);
    }
#pragma unroll
    for (int j = 0; j < 8; ++j) {
        float sq = s_q[b * Qn + j * 16 + lrow];
#pragma unroll
        for (int r = 0; r < 4; ++r) acc[j][r] += sq;
    }
    float lm[8], ls[8];
#pragma unroll
    for (int j = 0; j < 8; ++j) {
        float m = fmaxf(fmaxf(acc[j][0], acc[j][1]), fmaxf(acc[j][2], acc[j][3]));
        m = fmaxf(m, __shfl_xor(m, 16, 64));
        m = fmaxf(m, __shfl_xor(m, 32, 64));
        lm[j] = m;
        float s = __expf(acc[j][0] - m) + __expf(acc[j][1] - m)
                + __expf(acc[j][2] - m) + __expf(acc[j][3] - m);
        s += __shfl_xor(s, 16, 64);
        s += __shfl_xor(s, 32, 64);
        ls[j] = s;
    }
    if (kg == 0) {
#pragma unroll
        for (int j = 0; j < 8; ++j) {
            colm4[w][j * 16 + lrow] = lm[j];
            cols4[w][j * 16 + lrow] = ls[j];
        }
    }
    __syncthreads();
    float mb[8];
#pragma unroll
    for (int j = 0; j < 8; ++j) {
        int q = j * 16 + lrow;
        float m = fmaxf(fmaxf(colm4[0][q], colm4[1][q]), fmaxf(colm4[2][q], colm4[3][q]));
        mb[j] = m;
        if (w == 0 && kg == 0) {
            float sb = cols4[0][q] * __expf(colm4[0][q] - m)
                     + cols4[1][q] * __expf(colm4[1][q] - m)
                     + cols4[2][q] * __expf(colm4[2][q] - m)
                     + cols4[3][q] * __expf(colm4[3][q] - m);
            cpM[(b * 32 + blk) * 128 + q] = m;
            cpS[(b * 32 + blk) * 128 + q] = sb;
        }
    }
#pragma unroll
    for (int j = 0; j < 8; ++j) {
        int q = j * 16 + lrow;
        ushort4 o;
        o.x = f2bf(__expf(acc[j][0] - mb[j]));
        o.y = f2bf(__expf(acc[j][1] - mb[j]));
        o.z = f2bf(__expf(acc[j][2] - mb[j]));
        o.w = f2bf(__expf(acc[j][3] - mb[j]));
        *(ushort4*)(ET + ((size_t)(b * Qn + q)) * Cn + c0 + w * 16 + kg * 4) = o;
    }
    size_t rowbase = (size_t)(b * Cn + c0 + w * 16 + kg * 4);
#pragma unroll
    for (int r = 0; r < 4; ++r) {
        float m = acc[0][r];
#pragma unroll
        for (int j = 1; j < 8; ++j) m = fmaxf(m, acc[j][r]);
        for (int d = 1; d < 16; d <<= 1) m = fmaxf(m, __shfl_xor(m, d, 64));
        float ssum = 0.f;
        float e[8];
#pragma unroll
        for (int j = 0; j < 8; ++j) {
            e[j] = __expf(acc[j][r] - m);
            ssum += e[j];
        }
        for (int d = 1; d < 16; d <<= 1) ssum += __shfl_xor(ssum, d, 64);
        float si = 1.f / ssum;
#pragma unroll
        for (int j = 0; j < 8; ++j)
            s1[(rowbase + r) * Qn + j * 16 + lrow] = f2bf(e[j] * si);
    }
}

// ---- k_a_part: a^T partials = xcT @ (ET*corr)^T; colcomb+corr fused -------
__global__ __launch_bounds__(256) void k_a_part(const unsigned short* __restrict__ ET,
                                                const unsigned short* __restrict__ xcT,
                                                const float* __restrict__ cpM,
                                                const float* __restrict__ cpS,
                                                float* __restrict__ aP) {
    int mt = blockIdx.x, ks = blockIdx.y, b = blockIdx.z;
    int tid = threadIdx.x;
    int w = tid >> 6, lane = tid & 63;
    int lrow = lane & 15, kg = lane >> 4;
    __shared__ float colMs[128], colSis[128];
    if (tid < 128) {
        int q = tid;
        float m = -1e30f;
        for (int k = 0; k < 32; k++) m = fmaxf(m, cpM[(b * 32 + k) * 128 + q]);
        float s = 0.f;
        for (int k = 0; k < 32; k++) s += cpS[(b * 32 + k) * 128 + q] * __expf(cpM[(b * 32 + k) * 128 + q] - m);
        colMs[q] = m;
        colSis[q] = 1.f / s;
    }
    __syncthreads();
    int q0 = w * 16 + lrow, q1 = q0 + 64;
    int cb0 = ks * 8;   // first 64-c chunk index in this K-512 slice
    float corr0[8], corr1[8];
#pragma unroll
    for (int i = 0; i < 8; ++i) {
        corr0[i] = __expf(cpM[(b * 32 + cb0 + i) * 128 + q0] - colMs[q0]) * colSis[q0];
        corr1[i] = __expf(cpM[(b * 32 + cb0 + i) * 128 + q1] - colMs[q1]) * colSis[q1];
    }
    const unsigned short* Ab = xcT + ((size_t)(b * EP + mt * 16 + lrow)) * Cn + ks * 512 + kg * 8;
    const unsigned short* B0 = ET + ((size_t)(b * Qn + q0)) * Cn + ks * 512 + kg * 8;
    const unsigned short* B1 = ET + ((size_t)(b * Qn + q1)) * Cn + ks * 512 + kg * 8;
    f32x4 acc0 = {}, acc1 = {};
#pragma unroll
    for (int kb = 0; kb < 4; ++kb) {
        bf16x8 af[4], bv0[4], bv1[4];
#pragma unroll
        for (int k4 = 0; k4 < 4; ++k4) {
            af[k4]  = *(const bf16x8*)(Ab + (kb * 4 + k4) * 32);
            bv0[k4] = *(const bf16x8*)(B0 + (kb * 4 + k4) * 32);
            bv1[k4] = *(const bf16x8*)(B1 + (kb * 4 + k4) * 32);
        }
#pragma unroll
        for (int k4 = 0; k4 < 4; ++k4) {
            bf16x8 s0 = scale8(bv0[k4], corr0[kb * 2 + (k4 >> 1)]);
            bf16x8 s1v = scale8(bv1[k4], corr1[kb * 2 + (k4 >> 1)]);
            acc0 = __builtin_amdgcn_mfma_f32_16x16x32_bf16(af[k4], s0, acc0, 0, 0, 0);
            acc1 = __builtin_amdgcn_mfma_f32_16x16x32_bf16(af[k4], s1v, acc1, 0, 0, 0);
        }
    }
    size_t ebase = (size_t)(b * 4 + ks) * EP + mt * 16 + kg * 4;
#pragma unroll
    for (int r = 0; r < 4; ++r) {
        aP[(ebase + r) * Qn + q0 - lrow + lrow] = acc0[r];  // = [ebase+r]*Qn + w*16+lrow
        aP[(ebase + r) * Qn + q1] = acc1[r];
    }
}

// ---- k_acomb2: sum 4 partials -> xqaT rows [200,400) ----------------------
__global__ void k_acomb2(const float* __restrict__ aP, unsigned short* __restrict__ xqaT) {
    int gid = blockIdx.x * 256 + threadIdx.x;
    if (gid >= Bn * En * Qn) return;
    int b = gid / (En * Qn), r = gid % (En * Qn);
    int e = r / Qn, q = r % Qn;
    float s = 0.f;
#pragma unroll
    for (int k = 0; k < 4; k++)
        s += aP[((size_t)(b * 4 + k) * EP + e) * Qn + q];
    xqaT[((size_t)(b * 400 + 200 + e)) * Qn + q] = f2bf(s);
}

// ---- phase-1 helper: wave owns NJ n-tiles, ALL 4 m-tiles (B reuse = 4) ----
template<int NJ>
__device__ __forceinline__ void cq_phase64(const unsigned short* __restrict__ s1t,
                                           const unsigned short* __restrict__ xqaT_b,
                                           unsigned short* __restrict__ feats,
                                           int J0, int kg, int lrow) {
    f32x4 acc[NJ][4];
#pragma unroll
    for (int j = 0; j < NJ; ++j)
#pragma unroll
        for (int m = 0; m < 4; ++m) acc[j][m] = f32x4{0.f, 0.f, 0.f, 0.f};
#pragma unroll
    for (int kc = 0; kc < 4; ++kc) {
        bf16x8 a[4];
#pragma unroll
        for (int m = 0; m < 4; ++m)
            a[m] = *(const bf16x8*)(s1t + (m * 16 + lrow) * 136 + kg * 8 + kc * 32);
        bf16x8 bv[NJ];
#pragma unroll
        for (int j = 0; j < NJ; ++j)
            bv[j] = *(const bf16x8*)(xqaT_b + ((size_t)((J0 + j) * 16 + lrow)) * Qn + kg * 8 + kc * 32);
#pragma unroll
        for (int j = 0; j < NJ; ++j)
#pragma unroll
            for (int m = 0; m < 4; ++m)
                acc[j][m] = __builtin_amdgcn_mfma_f32_16x16x32_bf16(a[m], bv[j], acc[j][m], 0, 0, 0);
    }
#pragma unroll
    for (int j = 0; j < NJ; ++j) {
        int col = (J0 + j) * 16 + lrow;
        int off = col + (col < 200 ? 200 : 400);
#pragma unroll
        for (int m = 0; m < 4; ++m)
#pragma unroll
            for (int r = 0; r < 4; ++r)
                feats[(m * 16 + kg * 4 + r) * 808 + off] = f2bf(acc[j][m][r]);
    }
}

// ---- k_tail: fused [c2q|q2c] + feats + projection, 64-row tiles -----------
__global__ __launch_bounds__(512, 2) void k_tail(const unsigned short* __restrict__ s1,
                                                 const unsigned short* __restrict__ xqaT,
                                                 const unsigned short* __restrict__ xcb,
                                                 const unsigned short* __restrict__ wpb,
                                                 const float* __restrict__ bp,
                                                 float* __restrict__ out) {
    int b = blockIdx.y, c0 = blockIdx.x * 64;
    int tid = threadIdx.x;
    int w = tid >> 6, lane = tid & 63;
    int lrow = lane & 15, kg = lane >> 4;
    __shared__ unsigned short s1t[64 * 136];
    __shared__ unsigned short feats[64 * 808];

    for (int i = tid; i < 64 * 16; i += 512) {
        int row = i >> 4, c8 = i & 15;
        *(bf16x8*)(s1t + row * 136 + c8 * 8) =
            *(const bf16x8*)(s1 + ((size_t)(b * Cn + c0 + row)) * Qn + c8 * 8);
    }
    for (int i = tid; i < 64 * 25; i += 512) {   // slot0 = xc_bf tile (bf16 direct)
        int row = i / 25, e8 = (i % 25) * 8;
        *(bf16x8*)(feats + row * 808 + e8) =
            *(const bf16x8*)(xcb + ((size_t)(b * Cn + c0 + row)) * En + e8);
    }
    __syncthreads();

    // phase 1: wave w owns n-tiles [3w, 3w+3) (wave 7: [21,25)), all 64 rows
    {
        const unsigned short* xqaT_b = xqaT + (size_t)b * 400 * Qn;
        if (w < 7) cq_phase64<3>(s1t, xqaT_b, feats, w * 3, kg, lrow);
        else       cq_phase64<4>(s1t, xqaT_b, feats, 21, kg, lrow);
    }
    __syncthreads();

    // mid-pass: slot2 = x*c2q, slot3 = x*q2c
    for (int i = tid; i < 64 * 25; i += 512) {
        int row = i / 25, e8 = (i % 25) * 8;
        unsigned short* fr = feats + row * 808;
        bf16x8 x  = *(bf16x8*)(fr + e8);
        bf16x8 c2 = *(bf16x8*)(fr + 200 + e8);
        bf16x8 q2 = *(bf16x8*)(fr + 600 + e8);
        *(bf16x8*)(fr + 400 + e8) = mul8(x, c2);
        *(bf16x8*)(fr + 600 + e8) = mul8(x, q2);
    }
    __syncthreads();

    // phase 2: wave w owns n-tile w (16 cols), all 4 m-tiles. B reuse = 4.
    {
        f32x4 acc[4] = {};
        const unsigned short* Bb = wpb + ((size_t)(w * 16 + lrow)) * Fn + kg * 8;
        const unsigned short* A0 = feats + lrow * 808 + kg * 8;
#pragma unroll
        for (int kc = 0; kc < 25; ++kc) {
            bf16x8 bfr = *(const bf16x8*)(Bb + kc * 32);
#pragma unroll
            for (int m = 0; m < 4; ++m) {
                bf16x8 af = *(const bf16x8*)(A0 + m * 16 * 808 + kc * 32);
                acc[m] = __builtin_amdgcn_mfma_f32_16x16x32_bf16(af, bfr, acc[m], 0, 0, 0);
            }
        }
        int o = w * 16 + lrow;
        float bpv = bp[o];
#pragma unroll
        for (int m = 0; m < 4; ++m)
#pragma unroll
            for (int r = 0; r < 4; ++r)
                out[((size_t)(b * Cn + c0 + m * 16 + kg * 4 + r)) * On + o] = acc[m][r] + bpv;
    }
}

extern "C" void kernel_launch(void* const* d_in, const int* in_sizes, int n_in,
                              void* d_out, int out_size, void* d_ws, size_t ws_size,
                              hipStream_t stream) {
    const float* xc = (const float*)d_in[0];
    const float* xq = (const float*)d_in[1];
    const float* wsim = (const float*)d_in[2];
    const float* wp = (const float*)d_in[3];
    const float* bp = (const float*)d_in[4];
    float* out = (float*)d_out;
    float* ws = (float*)d_ws;

    unsigned short* ET_bf   = (unsigned short*)ws;                 // 4,194,304 bf16
    unsigned short* s1_bf   = (unsigned short*)(ws + 2097152);     // 4,194,304 bf16
    unsigned short* xc_bf   = (unsigned short*)(ws + 4194304);     // 6,553,600 bf16 (alive thru k_tail)
    unsigned short* xcT_bf  = (unsigned short*)(ws + 7471104);     // 6,815,744 bf16
    unsigned short* yq_bf   = (unsigned short*)(ws + 10878976);    //   409,600 bf16
    unsigned short* xqaT_bf = (unsigned short*)(ws + 11083776);    //   819,200 bf16
    unsigned short* wp_bf   = (unsigned short*)(ws + 11493376);    //   102,400 bf16
    float* s_q   = ws + 11544576;   //     2,048 f
    float* cpM   = ws + 11546624;   //    65,536 f
    float* cpS   = ws + 11612160;   //    65,536 f
    float* aP    = ws + 11677696;   // 1,703,936 f
    // total: 13,381,632 floats = 53.5 MB (ws is ~268 MB per fill counter)

    k_prep_all<<<2788, 256, 0, stream>>>(xq, wsim, wp, xc, yq_bf, s_q, wp_bf, xqaT_bf, xc_bf, xcT_bf);
    k_scores_mfma<<<dim3(32, 16), 256, 0, stream>>>(xc_bf, yq_bf, s_q, ET_bf, s1_bf, cpM, cpS);
    k_a_part<<<dim3(13, 4, 16), 256, 0, stream>>>(ET_bf, xcT_bf, cpM, cpS, aP);
    k_acomb2<<<1600, 256, 0, stream>>>(aP, xqaT_bf);
    k_tail<<<dim3(32, 16), 512, 0, stream>>>(s1_bf, xqaT_bf, xc_bf, wp_bf, bp, out);
}